// Round 17
// baseline (1363.019 us; speedup 1.0000x reference)
//
#include <hip/hip_runtime.h>
#include <hip/hip_bf16.h>
#include <math.h>
#include <stdint.h>

#define D_MODEL 1024
#define D_STATE 128
#define D_INNER 2048
#define NCOLS   4352     // z(2048) + xm(2048) + B(128) + C(128); dt row handled separately
#define NB      4
#define TLEN    4096
#define BT      16384    // NB*TLEN
#define LCH     512      // chunk length
#define NCH     8        // TLEN/LCH

using bf16 = __hip_bfloat16;
typedef __attribute__((ext_vector_type(2))) float f32x2;
typedef __attribute__((ext_vector_type(4))) float f32x4;
typedef __attribute__((ext_vector_type(8))) short short8x;

// fast clipped-silu: v_exp + v_rcp (~1e-7 rel).  Additive paths only.
__device__ __forceinline__ float csilu_fast(float v) {
    float e = __expf(-v);
    float s = v * __builtin_amdgcn_rcpf(1.f + e);
    return fminf(s, 8.f);
}

__device__ __forceinline__ void gload_lds16(const void* g, void* l) {
    __builtin_amdgcn_global_load_lds(
        (const __attribute__((address_space(1))) void*)g,
        (__attribute__((address_space(3))) void*)l, 16, 0, 0);
}

// ---------------- f32 -> bf16 cast ----------------
__global__ __launch_bounds__(256) void cast_kernel(const float* __restrict__ src,
                                                   bf16* __restrict__ dst, int n4) {
    int i = blockIdx.x * 256 + threadIdx.x;
    if (i < n4) {
        float4 v = ((const float4*)src)[i];
        dst[i*4+0] = __float2bfloat16(v.x);
        dst[i*4+1] = __float2bfloat16(v.y);
        dst[i*4+2] = __float2bfloat16(v.z);
        dst[i*4+3] = __float2bfloat16(v.w);
    }
}

// ---------------- f32 -> (hi, lo) bf16 split ----------------
__global__ __launch_bounds__(256) void split_kernel(const float* __restrict__ src,
                                                    bf16* __restrict__ hi,
                                                    bf16* __restrict__ lo, int n4) {
    int i = blockIdx.x * 256 + threadIdx.x;
    if (i < n4) {
        float4 v = ((const float4*)src)[i];
        #pragma unroll
        for (int j = 0; j < 4; ++j) {
            float f = (&v.x)[j];
            bf16 h = __float2bfloat16(f);
            hi[i*4+j] = h;
            lo[i*4+j] = __float2bfloat16(f - __bfloat162float(h));
        }
    }
}

// ---------------- GEMM1 split-bf16 MFMA: zxbcdt = x @ in_w^T ----------------
__global__ __launch_bounds__(256) void gemm1_split(const bf16* __restrict__ Ah,
                                                   const bf16* __restrict__ Al,
                                                   const bf16* __restrict__ Bh,
                                                   const bf16* __restrict__ Bl,
                                                   bf16* __restrict__ zdst,
                                                   float* __restrict__ xmdst,
                                                   float* __restrict__ bcdst) {
    const int K = D_MODEL;
    __shared__ __align__(16) bf16 sAh[128*32], sAl[128*32];
    __shared__ __align__(16) bf16 sBh[128*32], sBl[128*32];
    const int tid  = threadIdx.x;
    const int lane = tid & 63;
    const int wave = tid >> 6;
    const int wr   = (wave >> 1) * 64;
    const int wc   = (wave & 1) * 64;
    const long arow0 = (long)blockIdx.x * 128;
    const long brow0 = (long)blockIdx.y * 128;
    const long kb = (long)K * 2;
    const bool prec = (blockIdx.y >= 16);
    const char* gAh = (const char*)Ah;
    const char* gAl = (const char*)Al;
    const char* gBh = (const char*)Bh;
    const char* gBl = (const char*)Bl;

    f32x4 acc[4][4] = {};
    const int c1 = tid, c2 = tid + 256;
    const long aoff1 = (arow0 + (c1 >> 2)) * kb + (c1 & 3) * 16;
    const long aoff2 = (arow0 + (c2 >> 2)) * kb + (c2 & 3) * 16;
    const long boff1 = (brow0 + (c1 >> 2)) * kb + (c1 & 3) * 16;
    const long boff2 = (brow0 + (c2 >> 2)) * kb + (c2 & 3) * 16;

    for (int k0 = 0; k0 < K; k0 += 32) {
        __syncthreads();
        const long kk = (long)k0 * 2;
        gload_lds16(gAh + aoff1 + kk, (char*)sAh + c1*16);
        gload_lds16(gAh + aoff2 + kk, (char*)sAh + c2*16);
        gload_lds16(gBh + boff1 + kk, (char*)sBh + c1*16);
        gload_lds16(gBh + boff2 + kk, (char*)sBh + c2*16);
        if (prec) {
            gload_lds16(gAl + aoff1 + kk, (char*)sAl + c1*16);
            gload_lds16(gAl + aoff2 + kk, (char*)sAl + c2*16);
            gload_lds16(gBl + boff1 + kk, (char*)sBl + c1*16);
            gload_lds16(gBl + boff2 + kk, (char*)sBl + c2*16);
        }
        __syncthreads();

        const int r    = lane & 15;
        const int koff = (lane >> 4) * 8;
        short8x ah[4], bh[4];
        #pragma unroll
        for (int m = 0; m < 4; ++m)
            ah[m] = *(const short8x*)(sAh + (wr + m*16 + r) * 32 + koff);
        #pragma unroll
        for (int n = 0; n < 4; ++n)
            bh[n] = *(const short8x*)(sBh + (wc + n*16 + r) * 32 + koff);
        if (prec) {
            short8x al[4], bl[4];
            #pragma unroll
            for (int m = 0; m < 4; ++m)
                al[m] = *(const short8x*)(sAl + (wr + m*16 + r) * 32 + koff);
            #pragma unroll
            for (int n = 0; n < 4; ++n)
                bl[n] = *(const short8x*)(sBl + (wc + n*16 + r) * 32 + koff);
            #pragma unroll
            for (int m = 0; m < 4; ++m)
                #pragma unroll
                for (int n = 0; n < 4; ++n) {
                    acc[m][n] = __builtin_amdgcn_mfma_f32_16x16x32_bf16(ah[m], bh[n], acc[m][n], 0, 0, 0);
                    acc[m][n] = __builtin_amdgcn_mfma_f32_16x16x32_bf16(ah[m], bl[n], acc[m][n], 0, 0, 0);
                    acc[m][n] = __builtin_amdgcn_mfma_f32_16x16x32_bf16(al[m], bh[n], acc[m][n], 0, 0, 0);
                }
        } else {
            #pragma unroll
            for (int m = 0; m < 4; ++m)
                #pragma unroll
                for (int n = 0; n < 4; ++n)
                    acc[m][n] = __builtin_amdgcn_mfma_f32_16x16x32_bf16(ah[m], bh[n], acc[m][n], 0, 0, 0);
        }
    }

    const int r4 = (lane >> 4) * 4;
    const int cl = lane & 15;
    if (blockIdx.y < 16) {
        #pragma unroll
        for (int m = 0; m < 4; ++m)
            #pragma unroll
            for (int n = 0; n < 4; ++n) {
                const long row = arow0 + wr + m*16 + r4;
                const long col = brow0 + wc + n*16 + cl;
                #pragma unroll
                for (int j = 0; j < 4; ++j)
                    zdst[(row + j) * 2048 + col] = __float2bfloat16(acc[m][n][j]);
            }
    } else if (blockIdx.y < 32) {
        #pragma unroll
        for (int m = 0; m < 4; ++m)
            #pragma unroll
            for (int n = 0; n < 4; ++n) {
                const long row = arow0 + wr + m*16 + r4;
                const long col = brow0 - 2048 + wc + n*16 + cl;
                #pragma unroll
                for (int j = 0; j < 4; ++j)
                    xmdst[(row + j) * 2048 + col] = acc[m][n][j];
            }
    } else {
        #pragma unroll
        for (int m = 0; m < 4; ++m)
            #pragma unroll
            for (int n = 0; n < 4; ++n) {
                const long row = arow0 + wr + m*16 + r4;
                const long col = brow0 - 4096 + wc + n*16 + cl;
                #pragma unroll
                for (int j = 0; j < 4; ++j)
                    bcdst[(row + j) * 256 + col] = acc[m][n][j];
            }
    }
}

// ---------------- GEMM2 (m97 MFMA): out = ygated(bf16) @ w2b(bf16)^T ----------------
__global__ __launch_bounds__(256) void gemm2_mfma(const bf16* __restrict__ A,
                                                  const bf16* __restrict__ B,
                                                  float* __restrict__ C) {
    const int K = D_INNER;
    __shared__ __align__(16) bf16 sA[128*32];
    __shared__ __align__(16) bf16 sB[128*32];
    const int tid  = threadIdx.x;
    const int lane = tid & 63;
    const int wave = tid >> 6;
    const int wr   = (wave >> 1) * 64;
    const int wc   = (wave & 1) * 64;
    const long arow0 = (long)blockIdx.x * 128;
    const long brow0 = (long)blockIdx.y * 128;
    const long kb = (long)K * 2;
    const char* gA = (const char*)A;
    const char* gB = (const char*)B;

    f32x4 acc[4][4] = {};
    const int c1 = tid, c2 = tid + 256;
    for (int k0 = 0; k0 < K; k0 += 32) {
        __syncthreads();
        gload_lds16(gA + (arow0 + (c1 >> 2)) * kb + k0*2 + (c1 & 3) * 16, (char*)sA + c1*16);
        gload_lds16(gA + (arow0 + (c2 >> 2)) * kb + k0*2 + (c2 & 3) * 16, (char*)sA + c2*16);
        gload_lds16(gB + (brow0 + (c1 >> 2)) * kb + k0*2 + (c1 & 3) * 16, (char*)sB + c1*16);
        gload_lds16(gB + (brow0 + (c2 >> 2)) * kb + k0*2 + (c2 & 3) * 16, (char*)sB + c2*16);
        __syncthreads();

        const int r    = lane & 15;
        const int koff = (lane >> 4) * 8;
        short8x af[4], bfr[4];
        #pragma unroll
        for (int m = 0; m < 4; ++m)
            af[m] = *(const short8x*)(sA + (wr + m*16 + r) * 32 + koff);
        #pragma unroll
        for (int n = 0; n < 4; ++n)
            bfr[n] = *(const short8x*)(sB + (wc + n*16 + r) * 32 + koff);
        #pragma unroll
        for (int m = 0; m < 4; ++m)
            #pragma unroll
            for (int n = 0; n < 4; ++n)
                acc[m][n] = __builtin_amdgcn_mfma_f32_16x16x32_bf16(af[m], bfr[n], acc[m][n], 0, 0, 0);
    }

    const int r4 = (lane >> 4) * 4;
    const int cl = lane & 15;
    #pragma unroll
    for (int m = 0; m < 4; ++m) {
        #pragma unroll
        for (int n = 0; n < 4; ++n) {
            const long row = arow0 + wr + m*16 + r4;
            const long col = brow0 + wc + n*16 + cl;
            #pragma unroll
            for (int j = 0; j < 4; ++j)
                C[(row + j) * D_MODEL + col] = acc[m][n][j];
        }
    }
}

// ---------------- dt column in fp32 + softplus (accurate) ----------------
__global__ __launch_bounds__(256) void dt_gemv(const float* __restrict__ x,
                                               const float* __restrict__ wdt,
                                               float* __restrict__ dts) {
    const int row  = blockIdx.x * 4 + (threadIdx.x >> 6);
    const int lane = threadIdx.x & 63;
    const float4* xr = (const float4*)(x + (long)row * D_MODEL);
    const float4* wr = (const float4*)wdt;
    float acc = 0.f;
    for (int i = lane; i < D_MODEL/4; i += 64) {
        float4 a = xr[i], b = wr[i];
        acc += a.x*b.x + a.y*b.y + a.z*b.z + a.w*b.w;
    }
    for (int o = 32; o > 0; o >>= 1) acc += __shfl_down(acc, o);
    if (lane == 0)
        dts[row] = fmaxf(acc, 0.f) + log1pf(expf(-fabsf(acc)));
}

// ---------------- per-chunk (LCH=512) inclusive cumsum of dts ----------------
__global__ __launch_bounds__(LCH) void cumsum_chunks(const float* __restrict__ dts,
                                                     float* __restrict__ cumdt) {
    __shared__ float s[LCH];
    const int t = threadIdx.x;
    const long base = (long)blockIdx.x * LCH;
    s[t] = dts[base + t];
    __syncthreads();
    for (int o = 1; o < LCH; o <<= 1) {
        float v = (t >= o) ? s[t - o] : 0.f;
        __syncthreads();
        s[t] += v;
        __syncthreads();
    }
    cumdt[base + t] = s[t];
}

// ---------------- phase A: chunk-local scan + fused conv4, 2 channels/lane ----------------
// Wave q owns states [32q,32q+32); per-wave staging (no barrier).  Each lane
// processes channels d0=blk*128+dl and d1=d0+64: every a4/b4/c4 LDS read is
// reused for BOTH channels' pk-chains -> LDS reads per channel halve (the
// measured binding resource).  yred float2 (both channels), parity-buffered.
__global__ __launch_bounds__(256) void scan_local(const float* __restrict__ dts,
                                                  const float* __restrict__ bc,
                                                  const float* __restrict__ A_log,
                                                  const float* __restrict__ xm,
                                                  const float* __restrict__ cw,
                                                  const float* __restrict__ Dp,
                                                  bf16* __restrict__ ybuf,
                                                  float* __restrict__ hbuf) {
    const int tid = threadIdx.x;
    const int dl  = tid & 63;           // lane within wave
    const int q   = tid >> 6;           // wave id = s-quarter
    const int d0  = blockIdx.x * 128 + dl;
    const int d1  = d0 + 64;
    const int ch  = blockIdx.y;
    const int b   = blockIdx.z;
    const long row0 = (long)b * TLEN + ch * LCH;
    const int s0   = q * 32;
    const int scol = dl & 31;
    const int half = dl >> 5;
    const float As_l = -expf(A_log[s0 + scol]);

    const float w00 = cw[d0*4+0], w01 = cw[d0*4+1], w02 = cw[d0*4+2], w03 = cw[d0*4+3];
    const float w10 = cw[d1*4+0], w11 = cw[d1*4+1], w12 = cw[d1*4+2], w13 = cw[d1*4+3];
    const float dpv0 = Dp[d0], dpv1 = Dp[d1];

    float p00 = 0.f, p01 = 0.f, p02 = 0.f;   // conv window channel d0
    float p10 = 0.f, p11 = 0.f, p12 = 0.f;   // conv window channel d1
    if (ch != 0) {
        p00 = csilu_fast(xm[(row0 - 3) * 2048 + d0]);
        p01 = csilu_fast(xm[(row0 - 2) * 2048 + d0]);
        p02 = csilu_fast(xm[(row0 - 1) * 2048 + d0]);
        p10 = csilu_fast(xm[(row0 - 3) * 2048 + d1]);
        p11 = csilu_fast(xm[(row0 - 2) * 2048 + d1]);
        p12 = csilu_fast(xm[(row0 - 1) * 2048 + d1]);
    }

    f32x2 hA[16], hB[16];                    // states for d0, d1 (16 f32x2 = 32 states each)
    #pragma unroll
    for (int k = 0; k < 16; ++k) { hA[k] = (f32x2){0.f,0.f}; hB[k] = (f32x2){0.f,0.f}; }

    __shared__ __align__(16) float sa[8][128], sb[8][128], sc[8][128];   // 12 KB
    __shared__ __align__(16) f32x2 yred[2][8][4][64];                    // 32 KB, parity
    int pbuf = 0;

    for (int tt = 0; tt < LCH; tt += 8) {
        // per-wave staging: lane covers rows {half, half+2, half+4, half+6}, col s0+scol
        #pragma unroll
        for (int k = 0; k < 4; ++k) {
            const int r = half + k*2;
            const long row = row0 + tt + r;
            const float dt = dts[row];
            const int sg = s0 + scol;
            sa[r][sg] = __expf(As_l * dt);
            sb[r][sg] = bc[row*256 + sg] * dt;       // B_bar
            sc[r][sg] = bc[row*256 + 128 + sg];      // raw C
        }
        #pragma unroll
        for (int r = 0; r < 8; ++r) {
            const long row = row0 + tt + r;
            const float cur0 = csilu_fast(xm[row * 2048 + d0]);
            const float cur1 = csilu_fast(xm[row * 2048 + d1]);
            const float xc0  = csilu_fast(w00*p00 + w01*p01 + w02*p02 + w03*cur0);
            const float xc1  = csilu_fast(w10*p10 + w11*p11 + w12*p12 + w13*cur1);
            p00 = p01; p01 = p02; p02 = cur0;
            p10 = p11; p11 = p12; p12 = cur1;
            const f32x2 x0 = (f32x2){xc0, xc0};
            const f32x2 x1 = (f32x2){xc1, xc1};
            f32x2 yA0 = {0.f,0.f}, yB0 = {0.f,0.f};
            f32x2 yA1 = {0.f,0.f}, yB1 = {0.f,0.f};
            #pragma unroll
            for (int k = 0; k < 8; ++k) {            // 4 states per iter (2x f32x2), 2 channels
                const f32x4 a4 = *(const f32x4*)&sa[r][s0 + k*4];
                const f32x4 b4 = *(const f32x4*)&sb[r][s0 + k*4];
                const f32x4 c4 = *(const f32x4*)&sc[r][s0 + k*4];
                const f32x2 aL = {a4.x, a4.y}, aH = {a4.z, a4.w};
                const f32x2 bL = {b4.x, b4.y}, bH = {b4.z, b4.w};
                const f32x2 cL = {c4.x, c4.y}, cH = {c4.z, c4.w};
                hA[k*2+0] = aL * hA[k*2+0] + bL * x0;
                hA[k*2+1] = aH * hA[k*2+1] + bH * x0;
                hB[k*2+0] = aL * hB[k*2+0] + bL * x1;
                hB[k*2+1] = aH * hB[k*2+1] + bH * x1;
                yA0 = hA[k*2+0] * cL + yA0;
                yB0 = hA[k*2+1] * cH + yB0;
                yA1 = hB[k*2+0] * cL + yA1;
                yB1 = hB[k*2+1] * cH + yB1;
            }
            f32x2 ypair;
            ypair.x = (yA0.x + yA0.y) + (yB0.x + yB0.y) + (q == 0 ? dpv0 * xc0 : 0.f);
            ypair.y = (yA1.x + yA1.y) + (yB1.x + yB1.y) + (q == 0 ? dpv1 * xc1 : 0.f);
            yred[pbuf][r][q][dl] = ypair;
        }
        __syncthreads();                         // all waves' yred[pbuf] writes visible
        #pragma unroll
        for (int i2 = 0; i2 < 4; ++i2) {         // 8 rows x 128 ch = 1024 outputs / 256 thr
            const int i = tid + i2 * 256;
            const int r = i >> 7, c = i & 127;
            const int cl2 = c & 63;
            float y = 0.f;
            if (c < 64) {
                #pragma unroll
                for (int q2 = 0; q2 < 4; ++q2) y += yred[pbuf][r][q2][cl2].x;
            } else {
                #pragma unroll
                for (int q2 = 0; q2 < 4; ++q2) y += yred[pbuf][r][q2][cl2].y;
            }
            ybuf[(row0 + tt + r) * 2048 + blockIdx.x * 128 + c] = __float2bfloat16(y);
        }
        pbuf ^= 1;                               // next tile writes other parity
    }
    // chunk-final h, transposed layout [d][s]
    const long hb0 = ((long)(b * NCH + ch) * 2048 + d0) * 128;
    const long hb1 = ((long)(b * NCH + ch) * 2048 + d1) * 128;
    #pragma unroll
    for (int k = 0; k < 8; ++k) {
        *(float4*)&hbuf[hb0 + s0 + k*4] = make_float4(hA[k*2].x, hA[k*2].y, hA[k*2+1].x, hA[k*2+1].y);
        *(float4*)&hbuf[hb1 + s0 + k*4] = make_float4(hB[k*2].x, hB[k*2].y, hB[k*2+1].x, hB[k*2+1].y);
    }
}

// ---------------- phase B: cross-chunk combine; h_in -> hi/lo bf16 (transposed) + hT ----------------
__global__ __launch_bounds__(256) void scan_comb(const float* __restrict__ hbuf,
                                                 const float* __restrict__ cumdt,
                                                 const float* __restrict__ A_log,
                                                 bf16* __restrict__ hinH,
                                                 bf16* __restrict__ hinL,
                                                 float* __restrict__ hT) {
    const long idx = (long)blockIdx.x * 256 + threadIdx.x;   // over B*D*S, s fastest
    const int s = (int)(idx & 127);
    const int d = (int)((idx >> 7) & 2047);
    const int b = (int)(idx >> 18);
    const float As = -expf(A_log[s]);
    float hr = 0.f;
    for (int c = 0; c < NCH; ++c) {
        const long off = ((long)(b * NCH + c) * 2048 + d) * 128 + s;
        const float loc = hbuf[off];
        const bf16 hh = __float2bfloat16(hr);
        hinH[off] = hh;
        hinL[off] = __float2bfloat16(hr - __bfloat162float(hh));
        const float p = __expf(As * cumdt[(long)b * TLEN + c * LCH + (LCH - 1)]);
        hr = p * hr + loc;
    }
    hT[((long)b * 2048 + d) * 128 + s] = hr;
}

// ---------------- phase C as GEMM: Y += Cmod(512x128) @ Hin(128x2048) per (b,ch) ----------------
__global__ __launch_bounds__(256) void corr_gemm(const float* __restrict__ cumdt,
                                                 const float* __restrict__ bc,
                                                 const float* __restrict__ A_log,
                                                 const bf16* __restrict__ hinH,
                                                 const bf16* __restrict__ hinL,
                                                 bf16* __restrict__ ybuf) {
    __shared__ __align__(16) bf16 sA[128*32];
    __shared__ __align__(16) bf16 sBh[128*32], sBl[128*32];
    const int tid  = threadIdx.x;
    const int lane = tid & 63;
    const int wave = tid >> 6;
    const int wr   = (wave >> 1) * 64;
    const int wc   = (wave & 1) * 64;
    const long arow0 = (long)blockIdx.x * 128;      // rows over BT (within one 512-chunk)
    const long bcol0 = (long)blockIdx.y * 128;      // channels
    const int b  = (int)(arow0 >> 12);
    const int ch = (int)((arow0 & 4095) >> 9);
    const char* gH = (const char*)(hinH + (long)(b * NCH + ch) * 2048 * 128);
    const char* gL = (const char*)(hinL + (long)(b * NCH + ch) * 2048 * 128);

    f32x4 acc[4][4] = {};
    const int c1 = tid, c2 = tid + 256;
    for (int k0 = 0; k0 < 128; k0 += 32) {
        __syncthreads();
        {
            const int r   = tid >> 1;
            const int kk0 = (tid & 1) * 16;
            const long row = arow0 + r;
            const float cd = cumdt[row];
            #pragma unroll
            for (int t2 = 0; t2 < 16; ++t2) {
                const int s = k0 + kk0 + t2;
                const float As = -__expf(A_log[s]);
                const float cm = bc[row*256 + 128 + s] * __expf(As * cd);
                sA[r*32 + kk0 + t2] = __float2bfloat16(cm);
            }
        }
        gload_lds16(gH + (bcol0 + (c1 >> 2))*256 + k0*2 + (c1 & 3)*16, (char*)sBh + c1*16);
        gload_lds16(gH + (bcol0 + (c2 >> 2))*256 + k0*2 + (c2 & 3)*16, (char*)sBh + c2*16);
        gload_lds16(gL + (bcol0 + (c1 >> 2))*256 + k0*2 + (c1 & 3)*16, (char*)sBl + c1*16);
        gload_lds16(gL + (bcol0 + (c2 >> 2))*256 + k0*2 + (c2 & 3)*16, (char*)sBl + c2*16);
        __syncthreads();

        const int r    = lane & 15;
        const int koff = (lane >> 4) * 8;
        short8x af[4], bh[4], bl[4];
        #pragma unroll
        for (int m = 0; m < 4; ++m)
            af[m] = *(const short8x*)(sA + (wr + m*16 + r) * 32 + koff);
        #pragma unroll
        for (int n = 0; n < 4; ++n) {
            bh[n] = *(const short8x*)(sBh + (wc + n*16 + r) * 32 + koff);
            bl[n] = *(const short8x*)(sBl + (wc + n*16 + r) * 32 + koff);
        }
        #pragma unroll
        for (int m = 0; m < 4; ++m)
            #pragma unroll
            for (int n = 0; n < 4; ++n) {
                acc[m][n] = __builtin_amdgcn_mfma_f32_16x16x32_bf16(af[m], bh[n], acc[m][n], 0, 0, 0);
                acc[m][n] = __builtin_amdgcn_mfma_f32_16x16x32_bf16(af[m], bl[n], acc[m][n], 0, 0, 0);
            }
    }

    const int r4 = (lane >> 4) * 4;
    const int cl = lane & 15;
    #pragma unroll
    for (int m = 0; m < 4; ++m) {
        #pragma unroll
        for (int n = 0; n < 4; ++n) {
            const long row = arow0 + wr + m*16 + r4;
            const long col = bcol0 + wc + n*16 + cl;
            #pragma unroll
            for (int j = 0; j < 4; ++j) {
                const long o = (row + j) * 2048 + col;
                ybuf[o] = __float2bfloat16(__bfloat162float(ybuf[o]) + acc[m][n][j]);
            }
        }
    }
}

// ---------------- RMSNorm * norm_w * csilu(z): ygated bf16 written over z ----------------
__global__ __launch_bounds__(256) void rms_z(const bf16* __restrict__ ybuf,
                                             bf16* __restrict__ zg,
                                             const float* __restrict__ norm_w) {
    const long row = blockIdx.x;
    const int tid = threadIdx.x;
    float v[8];
    float ss = 0.f;
    #pragma unroll
    for (int i = 0; i < 8; ++i) {
        v[i] = __bfloat162float(ybuf[row * D_INNER + i*256 + tid]);
        ss += v[i] * v[i];
    }
    __shared__ float red[256];
    red[tid] = ss;
    __syncthreads();
    for (int o = 128; o > 0; o >>= 1) {
        if (tid < o) red[tid] += red[tid + o];
        __syncthreads();
    }
    const float scale = rsqrtf(red[0] * (1.f / D_INNER) + 1e-5f);
    #pragma unroll
    for (int i = 0; i < 8; ++i) {
        const int dd = i*256 + tid;
        const float z = __bfloat162float(zg[row * D_INNER + dd]);
        zg[row * D_INNER + dd] = __float2bfloat16(v[i] * scale * norm_w[dd] * csilu_fast(z));
    }
}

extern "C" void kernel_launch(void* const* d_in, const int* in_sizes, int n_in,
                              void* d_out, int out_size, void* d_ws, size_t ws_size,
                              hipStream_t stream) {
    const float* x      = (const float*)d_in[0];
    const float* in_w   = (const float*)d_in[1];   // (4353, 1024)
    const float* conv_w = (const float*)d_in[2];   // (2048, 1, 4)
    const float* A_log  = (const float*)d_in[3];   // (128,)
    const float* Dp     = (const float*)d_in[4];   // (2048,)
    const float* norm_w = (const float*)d_in[5];   // (2048,)
    const float* out_w  = (const float*)d_in[6];   // (1024, 2048)
    float* out = (float*)d_out;
    float* hT  = out + (long)BT * D_MODEL;

    char* ws = (char*)d_ws;
    size_t off = 0;
    auto alloc = [&](size_t bytes) { void* p = ws + off; off += (bytes + 255) & ~(size_t)255; return p; };
    bf16*  zg    = (bf16*) alloc((size_t)BT * D_INNER * 2);               //  67.1 MB: z -> ygated
    float* xm    = (float*)alloc((size_t)BT * D_INNER * 4);               // 134.2 MB: xm f32
    float* bcbuf = (float*)alloc((size_t)BT * 256 * 4);                   //  16.8 MB: B|C f32
    bf16*  w2b   = (bf16*) alloc((size_t)D_MODEL * D_INNER * 2);          //   4.2 MB
    float* hbuf  = (float*)alloc((size_t)NB * NCH * 128 * D_INNER * 4);   //  33.5 MB
    float* dts   = (float*)alloc((size_t)BT * 4);
    float* cumdt = (float*)alloc((size_t)BT * 4);
    // total ~256.0 MB (PROVEN).  Guarded.
    if (ws_size < off) return;

    // Aliases (lifetime-disjoint):
    bf16* whi = (bf16*)hbuf;                      // [split_w -> gemm1]; hbuf written by scan_local
    bf16* wlo = whi + (size_t)NCOLS * D_MODEL;
    bf16* xhi = (bf16*)d_out;                     // [split_x -> gemm1]
    bf16* xlo = xhi + (size_t)BT * D_MODEL;
    bf16* ybuf = (bf16*)d_out;                    // [scan_local -> rms_z], then gemm2 writes out
    bf16* hinH = (bf16*)xm;                       // [comb -> corr]; xm dead after scan_local
    bf16* hinL = hinH + (size_t)NB * NCH * D_INNER * 128;

    split_kernel<<<BT*D_MODEL/4/256, 256, 0, stream>>>(x, xhi, xlo, BT*D_MODEL/4);
    split_kernel<<<NCOLS*D_MODEL/4/256, 256, 0, stream>>>(in_w, whi, wlo, NCOLS*D_MODEL/4);
    cast_kernel<<<D_MODEL*D_INNER/4/256, 256, 0, stream>>>(out_w, w2b, D_MODEL*D_INNER/4);

    gemm1_split<<<dim3(BT/128, NCOLS/128), 256, 0, stream>>>(xhi, xlo, whi, wlo, zg, xm, bcbuf);
    dt_gemv<<<BT/4, 256, 0, stream>>>(x, in_w + (long)NCOLS * D_MODEL, dts);
    cumsum_chunks<<<NB*NCH, LCH, 0, stream>>>(dts, cumdt);
    scan_local<<<dim3(D_INNER/128, NCH, NB), 256, 0, stream>>>(dts, bcbuf, A_log, xm, conv_w, Dp, ybuf, hbuf);
    scan_comb<<<NB*128*D_INNER/256, 256, 0, stream>>>(hbuf, cumdt, A_log, hinH, hinL, hT);
    corr_gemm<<<dim3(BT/128, D_INNER/128), 256, 0, stream>>>(cumdt, bcbuf, A_log, hinH, hinL, ybuf);
    rms_z<<<BT, 256, 0, stream>>>(ybuf, zg, norm_w);
    gemm2_mfma<<<dim3(BT/128, D_MODEL/128), 256, 0, stream>>>(zg, w2b, out);
}

// Round 18
// 1129.298 us; speedup vs baseline: 1.2070x; 1.2070x over previous
//
#include <hip/hip_runtime.h>
#include <hip/hip_bf16.h>
#include <math.h>
#include <stdint.h>

#define D_MODEL 1024
#define D_STATE 128
#define D_INNER 2048
#define NCOLS   4352     // z(2048) + xm(2048) + B(128) + C(128); dt row handled separately
#define NB      4
#define TLEN    4096
#define BT      16384    // NB*TLEN
#define LCH     512      // chunk length
#define NCH     8        // TLEN/LCH

using bf16 = __hip_bfloat16;
typedef __attribute__((ext_vector_type(2))) float f32x2;
typedef __attribute__((ext_vector_type(4))) float f32x4;
typedef __attribute__((ext_vector_type(8))) short short8x;

// fast clipped-silu: v_exp + v_rcp (~1e-7 rel).  Additive paths only.
__device__ __forceinline__ float csilu_fast(float v) {
    float e = __expf(-v);
    float s = v * __builtin_amdgcn_rcpf(1.f + e);
    return fminf(s, 8.f);
}

__device__ __forceinline__ void gload_lds16(const void* g, void* l) {
    __builtin_amdgcn_global_load_lds(
        (const __attribute__((address_space(1))) void*)g,
        (__attribute__((address_space(3))) void*)l, 16, 0, 0);
}

// ---------------- f32 -> bf16 cast ----------------
__global__ __launch_bounds__(256) void cast_kernel(const float* __restrict__ src,
                                                   bf16* __restrict__ dst, int n4) {
    int i = blockIdx.x * 256 + threadIdx.x;
    if (i < n4) {
        float4 v = ((const float4*)src)[i];
        dst[i*4+0] = __float2bfloat16(v.x);
        dst[i*4+1] = __float2bfloat16(v.y);
        dst[i*4+2] = __float2bfloat16(v.z);
        dst[i*4+3] = __float2bfloat16(v.w);
    }
}

// ---------------- f32 -> (hi, lo) bf16 split ----------------
__global__ __launch_bounds__(256) void split_kernel(const float* __restrict__ src,
                                                    bf16* __restrict__ hi,
                                                    bf16* __restrict__ lo, int n4) {
    int i = blockIdx.x * 256 + threadIdx.x;
    if (i < n4) {
        float4 v = ((const float4*)src)[i];
        #pragma unroll
        for (int j = 0; j < 4; ++j) {
            float f = (&v.x)[j];
            bf16 h = __float2bfloat16(f);
            hi[i*4+j] = h;
            lo[i*4+j] = __float2bfloat16(f - __bfloat162float(h));
        }
    }
}

// ---------------- GEMM1 split-bf16 MFMA: zxbcdt = x @ in_w^T ----------------
__global__ __launch_bounds__(256) void gemm1_split(const bf16* __restrict__ Ah,
                                                   const bf16* __restrict__ Al,
                                                   const bf16* __restrict__ Bh,
                                                   const bf16* __restrict__ Bl,
                                                   bf16* __restrict__ zdst,
                                                   float* __restrict__ xmdst,
                                                   float* __restrict__ bcdst) {
    const int K = D_MODEL;
    __shared__ __align__(16) bf16 sAh[128*32], sAl[128*32];
    __shared__ __align__(16) bf16 sBh[128*32], sBl[128*32];
    const int tid  = threadIdx.x;
    const int lane = tid & 63;
    const int wave = tid >> 6;
    const int wr   = (wave >> 1) * 64;
    const int wc   = (wave & 1) * 64;
    const long arow0 = (long)blockIdx.x * 128;
    const long brow0 = (long)blockIdx.y * 128;
    const long kb = (long)K * 2;
    const bool prec = (blockIdx.y >= 16);
    const char* gAh = (const char*)Ah;
    const char* gAl = (const char*)Al;
    const char* gBh = (const char*)Bh;
    const char* gBl = (const char*)Bl;

    f32x4 acc[4][4] = {};
    const int c1 = tid, c2 = tid + 256;
    const long aoff1 = (arow0 + (c1 >> 2)) * kb + (c1 & 3) * 16;
    const long aoff2 = (arow0 + (c2 >> 2)) * kb + (c2 & 3) * 16;
    const long boff1 = (brow0 + (c1 >> 2)) * kb + (c1 & 3) * 16;
    const long boff2 = (brow0 + (c2 >> 2)) * kb + (c2 & 3) * 16;

    for (int k0 = 0; k0 < K; k0 += 32) {
        __syncthreads();
        const long kk = (long)k0 * 2;
        gload_lds16(gAh + aoff1 + kk, (char*)sAh + c1*16);
        gload_lds16(gAh + aoff2 + kk, (char*)sAh + c2*16);
        gload_lds16(gBh + boff1 + kk, (char*)sBh + c1*16);
        gload_lds16(gBh + boff2 + kk, (char*)sBh + c2*16);
        if (prec) {
            gload_lds16(gAl + aoff1 + kk, (char*)sAl + c1*16);
            gload_lds16(gAl + aoff2 + kk, (char*)sAl + c2*16);
            gload_lds16(gBl + boff1 + kk, (char*)sBl + c1*16);
            gload_lds16(gBl + boff2 + kk, (char*)sBl + c2*16);
        }
        __syncthreads();

        const int r    = lane & 15;
        const int koff = (lane >> 4) * 8;
        short8x ah[4], bh[4];
        #pragma unroll
        for (int m = 0; m < 4; ++m)
            ah[m] = *(const short8x*)(sAh + (wr + m*16 + r) * 32 + koff);
        #pragma unroll
        for (int n = 0; n < 4; ++n)
            bh[n] = *(const short8x*)(sBh + (wc + n*16 + r) * 32 + koff);
        if (prec) {
            short8x al[4], bl[4];
            #pragma unroll
            for (int m = 0; m < 4; ++m)
                al[m] = *(const short8x*)(sAl + (wr + m*16 + r) * 32 + koff);
            #pragma unroll
            for (int n = 0; n < 4; ++n)
                bl[n] = *(const short8x*)(sBl + (wc + n*16 + r) * 32 + koff);
            #pragma unroll
            for (int m = 0; m < 4; ++m)
                #pragma unroll
                for (int n = 0; n < 4; ++n) {
                    acc[m][n] = __builtin_amdgcn_mfma_f32_16x16x32_bf16(ah[m], bh[n], acc[m][n], 0, 0, 0);
                    acc[m][n] = __builtin_amdgcn_mfma_f32_16x16x32_bf16(ah[m], bl[n], acc[m][n], 0, 0, 0);
                    acc[m][n] = __builtin_amdgcn_mfma_f32_16x16x32_bf16(al[m], bh[n], acc[m][n], 0, 0, 0);
                }
        } else {
            #pragma unroll
            for (int m = 0; m < 4; ++m)
                #pragma unroll
                for (int n = 0; n < 4; ++n)
                    acc[m][n] = __builtin_amdgcn_mfma_f32_16x16x32_bf16(ah[m], bh[n], acc[m][n], 0, 0, 0);
        }
    }

    const int r4 = (lane >> 4) * 4;
    const int cl = lane & 15;
    if (blockIdx.y < 16) {
        #pragma unroll
        for (int m = 0; m < 4; ++m)
            #pragma unroll
            for (int n = 0; n < 4; ++n) {
                const long row = arow0 + wr + m*16 + r4;
                const long col = brow0 + wc + n*16 + cl;
                #pragma unroll
                for (int j = 0; j < 4; ++j)
                    zdst[(row + j) * 2048 + col] = __float2bfloat16(acc[m][n][j]);
            }
    } else if (blockIdx.y < 32) {
        #pragma unroll
        for (int m = 0; m < 4; ++m)
            #pragma unroll
            for (int n = 0; n < 4; ++n) {
                const long row = arow0 + wr + m*16 + r4;
                const long col = brow0 - 2048 + wc + n*16 + cl;
                #pragma unroll
                for (int j = 0; j < 4; ++j)
                    xmdst[(row + j) * 2048 + col] = acc[m][n][j];
            }
    } else {
        #pragma unroll
        for (int m = 0; m < 4; ++m)
            #pragma unroll
            for (int n = 0; n < 4; ++n) {
                const long row = arow0 + wr + m*16 + r4;
                const long col = brow0 - 4096 + wc + n*16 + cl;
                #pragma unroll
                for (int j = 0; j < 4; ++j)
                    bcdst[(row + j) * 256 + col] = acc[m][n][j];
            }
    }
}

// ---------------- GEMM2 (m97 MFMA): out = ygated(bf16) @ w2b(bf16)^T ----------------
__global__ __launch_bounds__(256) void gemm2_mfma(const bf16* __restrict__ A,
                                                  const bf16* __restrict__ B,
                                                  float* __restrict__ C) {
    const int K = D_INNER;
    __shared__ __align__(16) bf16 sA[128*32];
    __shared__ __align__(16) bf16 sB[128*32];
    const int tid  = threadIdx.x;
    const int lane = tid & 63;
    const int wave = tid >> 6;
    const int wr   = (wave >> 1) * 64;
    const int wc   = (wave & 1) * 64;
    const long arow0 = (long)blockIdx.x * 128;
    const long brow0 = (long)blockIdx.y * 128;
    const long kb = (long)K * 2;
    const char* gA = (const char*)A;
    const char* gB = (const char*)B;

    f32x4 acc[4][4] = {};
    const int c1 = tid, c2 = tid + 256;
    for (int k0 = 0; k0 < K; k0 += 32) {
        __syncthreads();
        gload_lds16(gA + (arow0 + (c1 >> 2)) * kb + k0*2 + (c1 & 3) * 16, (char*)sA + c1*16);
        gload_lds16(gA + (arow0 + (c2 >> 2)) * kb + k0*2 + (c2 & 3) * 16, (char*)sA + c2*16);
        gload_lds16(gB + (brow0 + (c1 >> 2)) * kb + k0*2 + (c1 & 3) * 16, (char*)sB + c1*16);
        gload_lds16(gB + (brow0 + (c2 >> 2)) * kb + k0*2 + (c2 & 3) * 16, (char*)sB + c2*16);
        __syncthreads();

        const int r    = lane & 15;
        const int koff = (lane >> 4) * 8;
        short8x af[4], bfr[4];
        #pragma unroll
        for (int m = 0; m < 4; ++m)
            af[m] = *(const short8x*)(sA + (wr + m*16 + r) * 32 + koff);
        #pragma unroll
        for (int n = 0; n < 4; ++n)
            bfr[n] = *(const short8x*)(sB + (wc + n*16 + r) * 32 + koff);
        #pragma unroll
        for (int m = 0; m < 4; ++m)
            #pragma unroll
            for (int n = 0; n < 4; ++n)
                acc[m][n] = __builtin_amdgcn_mfma_f32_16x16x32_bf16(af[m], bfr[n], acc[m][n], 0, 0, 0);
    }

    const int r4 = (lane >> 4) * 4;
    const int cl = lane & 15;
    #pragma unroll
    for (int m = 0; m < 4; ++m) {
        #pragma unroll
        for (int n = 0; n < 4; ++n) {
            const long row = arow0 + wr + m*16 + r4;
            const long col = brow0 + wc + n*16 + cl;
            #pragma unroll
            for (int j = 0; j < 4; ++j)
                C[(row + j) * D_MODEL + col] = acc[m][n][j];
        }
    }
}

// ---------------- dt column in fp32 + softplus (accurate) ----------------
__global__ __launch_bounds__(256) void dt_gemv(const float* __restrict__ x,
                                               const float* __restrict__ wdt,
                                               float* __restrict__ dts) {
    const int row  = blockIdx.x * 4 + (threadIdx.x >> 6);
    const int lane = threadIdx.x & 63;
    const float4* xr = (const float4*)(x + (long)row * D_MODEL);
    const float4* wr = (const float4*)wdt;
    float acc = 0.f;
    for (int i = lane; i < D_MODEL/4; i += 64) {
        float4 a = xr[i], b = wr[i];
        acc += a.x*b.x + a.y*b.y + a.z*b.z + a.w*b.w;
    }
    for (int o = 32; o > 0; o >>= 1) acc += __shfl_down(acc, o);
    if (lane == 0)
        dts[row] = fmaxf(acc, 0.f) + log1pf(expf(-fabsf(acc)));
}

// ---------------- per-chunk (LCH=512) inclusive cumsum of dts ----------------
__global__ __launch_bounds__(LCH) void cumsum_chunks(const float* __restrict__ dts,
                                                     float* __restrict__ cumdt) {
    __shared__ float s[LCH];
    const int t = threadIdx.x;
    const long base = (long)blockIdx.x * LCH;
    s[t] = dts[base + t];
    __syncthreads();
    for (int o = 1; o < LCH; o <<= 1) {
        float v = (t >= o) ? s[t - o] : 0.f;
        __syncthreads();
        s[t] += v;
        __syncthreads();
    }
    cumdt[base + t] = s[t];
}

// ---------------- phase A: R16 structure + one-tile-ahead register prefetch ----------------
// Wave q owns states [32q,32q+32); per-wave staging (no barrier); 1 barrier/tile.
// bc/dts/xm for tile t+1 are loaded into registers during tile t's compute, so
// staging is pure expf+ds_write from regs (global latency off the critical path).
__global__ __launch_bounds__(256) void scan_local(const float* __restrict__ dts,
                                                  const float* __restrict__ bc,
                                                  const float* __restrict__ A_log,
                                                  const float* __restrict__ xm,
                                                  const float* __restrict__ cw,
                                                  const float* __restrict__ Dp,
                                                  bf16* __restrict__ ybuf,
                                                  float* __restrict__ hbuf) {
    const int tid = threadIdx.x;
    const int dl  = tid & 63;           // lane within wave = channel slot
    const int q   = tid >> 6;           // wave id = s-quarter
    const int d   = blockIdx.x * 64 + dl;
    const int ch  = blockIdx.y;
    const int b   = blockIdx.z;
    const long row0 = (long)b * TLEN + ch * LCH;
    const int s0   = q * 32;
    const int scol = dl & 31;
    const int half = dl >> 5;
    const int sg   = s0 + scol;
    const float As_l = -expf(A_log[sg]);

    const float w0 = cw[d*4+0], w1 = cw[d*4+1], w2 = cw[d*4+2], w3 = cw[d*4+3];
    const float dpv = Dp[d];

    float p0 = 0.f, p1 = 0.f, p2 = 0.f;
    if (ch != 0) {
        p0 = csilu_fast(xm[(row0 - 3) * 2048 + d]);
        p1 = csilu_fast(xm[(row0 - 2) * 2048 + d]);
        p2 = csilu_fast(xm[(row0 - 1) * 2048 + d]);
    }

    f32x2 h2[16];
    #pragma unroll
    for (int k = 0; k < 16; ++k) h2[k] = (f32x2){0.f, 0.f};

    __shared__ __align__(16) float sa[8][128], sb[8][128], sc[8][128];   // 12 KB
    __shared__ __align__(16) float yred[2][8][4][64];                    // 16 KB, parity
    int pbuf = 0;

    // prologue: prefetch tile 0
    float pfDT[4], pfB[4], pfC[4], pfXM[8];
    #pragma unroll
    for (int k = 0; k < 4; ++k) {
        const long row = row0 + half + k*2;
        pfDT[k] = dts[row];
        pfB[k]  = bc[row*256 + sg];
        pfC[k]  = bc[row*256 + 128 + sg];
    }
    #pragma unroll
    for (int r = 0; r < 8; ++r) pfXM[r] = xm[(row0 + r) * 2048 + d];

    for (int tt = 0; tt < LCH; tt += 8) {
        // stage current tile from registers (no global on critical path)
        #pragma unroll
        for (int k = 0; k < 4; ++k) {
            const int r = half + k*2;
            sa[r][sg] = __expf(As_l * pfDT[k]);
            sb[r][sg] = pfB[k] * pfDT[k];       // B_bar
            sc[r][sg] = pfC[k];                 // raw C
        }
        float curXM[8];
        #pragma unroll
        for (int r = 0; r < 8; ++r) curXM[r] = pfXM[r];
        // issue next tile's loads (in flight under the compute below)
        if (tt + 8 < LCH) {
            #pragma unroll
            for (int k = 0; k < 4; ++k) {
                const long row = row0 + tt + 8 + half + k*2;
                pfDT[k] = dts[row];
                pfB[k]  = bc[row*256 + sg];
                pfC[k]  = bc[row*256 + 128 + sg];
            }
            #pragma unroll
            for (int r = 0; r < 8; ++r) pfXM[r] = xm[(row0 + tt + 8 + r) * 2048 + d];
        }
        #pragma unroll
        for (int r = 0; r < 8; ++r) {
            const float cur = csilu_fast(curXM[r]);
            const float xc  = csilu_fast(w0*p0 + w1*p1 + w2*p2 + w3*cur);
            p0 = p1; p1 = p2; p2 = cur;
            const f32x2 xc2 = (f32x2){xc, xc};
            f32x2 yA = (f32x2){0.f, 0.f}, yB = (f32x2){0.f, 0.f};
            #pragma unroll
            for (int k = 0; k < 8; ++k) {
                const f32x4 a4 = *(const f32x4*)&sa[r][s0 + k*4];
                const f32x4 b4 = *(const f32x4*)&sb[r][s0 + k*4];
                const f32x4 c4 = *(const f32x4*)&sc[r][s0 + k*4];
                const f32x2 aL = {a4.x, a4.y}, aH = {a4.z, a4.w};
                const f32x2 bL = {b4.x, b4.y}, bH = {b4.z, b4.w};
                const f32x2 cL = {c4.x, c4.y}, cH = {c4.z, c4.w};
                h2[k*2+0] = aL * h2[k*2+0] + bL * xc2;   // v_pk_fma_f32
                h2[k*2+1] = aH * h2[k*2+1] + bH * xc2;
                yA = h2[k*2+0] * cL + yA;
                yB = h2[k*2+1] * cH + yB;
            }
            yred[pbuf][r][q][dl] = (yA.x + yA.y) + (yB.x + yB.y) + (q == 0 ? dpv * xc : 0.f);
        }
        __syncthreads();                         // all waves' yred[pbuf] writes visible
        #pragma unroll
        for (int i2 = 0; i2 < 2; ++i2) {
            const int i = tid + i2 * 256;
            const int r = i >> 6, dl2 = i & 63;
            const float y = yred[pbuf][r][0][dl2] + yred[pbuf][r][1][dl2]
                          + yred[pbuf][r][2][dl2] + yred[pbuf][r][3][dl2];
            ybuf[(row0 + tt + r) * 2048 + blockIdx.x * 64 + dl2] = __float2bfloat16(y);
        }
        pbuf ^= 1;                               // parity: no second barrier
    }
    // chunk-final h, transposed layout [d][s]
    const long hb = ((long)(b * NCH + ch) * 2048 + d) * 128;
    #pragma unroll
    for (int k = 0; k < 8; ++k)
        *(float4*)&hbuf[hb + s0 + k*4] = make_float4(h2[k*2].x, h2[k*2].y, h2[k*2+1].x, h2[k*2+1].y);
}

// ---------------- phase B: cross-chunk combine; h_in -> hi/lo bf16 (transposed) + hT ----------------
__global__ __launch_bounds__(256) void scan_comb(const float* __restrict__ hbuf,
                                                 const float* __restrict__ cumdt,
                                                 const float* __restrict__ A_log,
                                                 bf16* __restrict__ hinH,
                                                 bf16* __restrict__ hinL,
                                                 float* __restrict__ hT) {
    const long idx = (long)blockIdx.x * 256 + threadIdx.x;   // over B*D*S, s fastest
    const int s = (int)(idx & 127);
    const int d = (int)((idx >> 7) & 2047);
    const int b = (int)(idx >> 18);
    const float As = -expf(A_log[s]);
    float hr = 0.f;
    for (int c = 0; c < NCH; ++c) {
        const long off = ((long)(b * NCH + c) * 2048 + d) * 128 + s;
        const float loc = hbuf[off];
        const bf16 hh = __float2bfloat16(hr);
        hinH[off] = hh;
        hinL[off] = __float2bfloat16(hr - __bfloat162float(hh));
        const float p = __expf(As * cumdt[(long)b * TLEN + c * LCH + (LCH - 1)]);
        hr = p * hr + loc;
    }
    hT[((long)b * 2048 + d) * 128 + s] = hr;
}

// ---------------- Cmod precompute: cmod[row,s] = C[row,s] * exp(As*cumdt[row]) (bf16) ----------------
__global__ __launch_bounds__(256) void cmod_build(const float* __restrict__ cumdt,
                                                  const float* __restrict__ bc,
                                                  const float* __restrict__ A_log,
                                                  bf16* __restrict__ cmod) {
    const long i = (long)blockIdx.x * 256 + threadIdx.x;   // over BT*128
    const int s = (int)(i & 127);
    const long row = i >> 7;
    const float As = -__expf(A_log[s]);
    cmod[i] = __float2bfloat16(bc[row*256 + 128 + s] * __expf(As * cumdt[row]));
}

// ---------------- phase C as GEMM: Y += Cmod(512x128) @ Hin(128x2048) per (b,ch) ----------------
__global__ __launch_bounds__(256) void corr_gemm(const bf16* __restrict__ cmod,
                                                 const bf16* __restrict__ hinH,
                                                 const bf16* __restrict__ hinL,
                                                 bf16* __restrict__ ybuf) {
    __shared__ __align__(16) bf16 sA[128*32];
    __shared__ __align__(16) bf16 sBh[128*32], sBl[128*32];
    const int tid  = threadIdx.x;
    const int lane = tid & 63;
    const int wave = tid >> 6;
    const int wr   = (wave >> 1) * 64;
    const int wc   = (wave & 1) * 64;
    const long arow0 = (long)blockIdx.x * 128;      // rows over BT (within one 512-chunk)
    const long bcol0 = (long)blockIdx.y * 128;      // channels
    const int b  = (int)(arow0 >> 12);
    const int ch = (int)((arow0 & 4095) >> 9);
    const char* gA = (const char*)cmod;             // [BT][128] bf16, 256 B rows
    const char* gH = (const char*)(hinH + (long)(b * NCH + ch) * 2048 * 128);
    const char* gL = (const char*)(hinL + (long)(b * NCH + ch) * 2048 * 128);

    f32x4 acc[4][4] = {};
    const int c1 = tid, c2 = tid + 256;
    for (int k0 = 0; k0 < 128; k0 += 32) {
        __syncthreads();
        gload_lds16(gA + (arow0 + (c1 >> 2))*256 + k0*2 + (c1 & 3)*16, (char*)sA + c1*16);
        gload_lds16(gA + (arow0 + (c2 >> 2))*256 + k0*2 + (c2 & 3)*16, (char*)sA + c2*16);
        gload_lds16(gH + (bcol0 + (c1 >> 2))*256 + k0*2 + (c1 & 3)*16, (char*)sBh + c1*16);
        gload_lds16(gH + (bcol0 + (c2 >> 2))*256 + k0*2 + (c2 & 3)*16, (char*)sBh + c2*16);
        gload_lds16(gL + (bcol0 + (c1 >> 2))*256 + k0*2 + (c1 & 3)*16, (char*)sBl + c1*16);
        gload_lds16(gL + (bcol0 + (c2 >> 2))*256 + k0*2 + (c2 & 3)*16, (char*)sBl + c2*16);
        __syncthreads();

        const int r    = lane & 15;
        const int koff = (lane >> 4) * 8;
        short8x af[4], bh[4], bl[4];
        #pragma unroll
        for (int m = 0; m < 4; ++m)
            af[m] = *(const short8x*)(sA + (wr + m*16 + r) * 32 + koff);
        #pragma unroll
        for (int n = 0; n < 4; ++n) {
            bh[n] = *(const short8x*)(sBh + (wc + n*16 + r) * 32 + koff);
            bl[n] = *(const short8x*)(sBl + (wc + n*16 + r) * 32 + koff);
        }
        #pragma unroll
        for (int m = 0; m < 4; ++m)
            #pragma unroll
            for (int n = 0; n < 4; ++n) {
                acc[m][n] = __builtin_amdgcn_mfma_f32_16x16x32_bf16(af[m], bh[n], acc[m][n], 0, 0, 0);
                acc[m][n] = __builtin_amdgcn_mfma_f32_16x16x32_bf16(af[m], bl[n], acc[m][n], 0, 0, 0);
            }
    }

    const int r4 = (lane >> 4) * 4;
    const int cl = lane & 15;
    #pragma unroll
    for (int m = 0; m < 4; ++m) {
        #pragma unroll
        for (int n = 0; n < 4; ++n) {
            const long row = arow0 + wr + m*16 + r4;
            const long col = bcol0 + wc + n*16 + cl;
            #pragma unroll
            for (int j = 0; j < 4; ++j) {
                const long o = (row + j) * 2048 + col;
                ybuf[o] = __float2bfloat16(__bfloat162float(ybuf[o]) + acc[m][n][j]);
            }
        }
    }
}

// ---------------- RMSNorm * norm_w * csilu(z): ygated bf16 written over z ----------------
__global__ __launch_bounds__(256) void rms_z(const bf16* __restrict__ ybuf,
                                             bf16* __restrict__ zg,
                                             const float* __restrict__ norm_w) {
    const long row = blockIdx.x;
    const int tid = threadIdx.x;
    float v[8];
    float ss = 0.f;
    #pragma unroll
    for (int i = 0; i < 8; ++i) {
        v[i] = __bfloat162float(ybuf[row * D_INNER + i*256 + tid]);
        ss += v[i] * v[i];
    }
    __shared__ float red[256];
    red[tid] = ss;
    __syncthreads();
    for (int o = 128; o > 0; o >>= 1) {
        if (tid < o) red[tid] += red[tid + o];
        __syncthreads();
    }
    const float scale = rsqrtf(red[0] * (1.f / D_INNER) + 1e-5f);
    #pragma unroll
    for (int i = 0; i < 8; ++i) {
        const int dd = i*256 + tid;
        const float z = __bfloat162float(zg[row * D_INNER + dd]);
        zg[row * D_INNER + dd] = __float2bfloat16(v[i] * scale * norm_w[dd] * csilu_fast(z));
    }
}

extern "C" void kernel_launch(void* const* d_in, const int* in_sizes, int n_in,
                              void* d_out, int out_size, void* d_ws, size_t ws_size,
                              hipStream_t stream) {
    const float* x      = (const float*)d_in[0];
    const float* in_w   = (const float*)d_in[1];   // (4353, 1024)
    const float* conv_w = (const float*)d_in[2];   // (2048, 1, 4)
    const float* A_log  = (const float*)d_in[3];   // (128,)
    const float* Dp     = (const float*)d_in[4];   // (2048,)
    const float* norm_w = (const float*)d_in[5];   // (2048,)
    const float* out_w  = (const float*)d_in[6];   // (1024, 2048)
    float* out = (float*)d_out;
    float* hT  = out + (long)BT * D_MODEL;

    char* ws = (char*)d_ws;
    size_t off = 0;
    auto alloc = [&](size_t bytes) { void* p = ws + off; off += (bytes + 255) & ~(size_t)255; return p; };
    bf16*  zg    = (bf16*) alloc((size_t)BT * D_INNER * 2);               //  67.1 MB: z -> ygated
    float* xm    = (float*)alloc((size_t)BT * D_INNER * 4);               // 134.2 MB: xm f32
    float* bcbuf = (float*)alloc((size_t)BT * 256 * 4);                   //  16.8 MB: B|C f32
    bf16*  w2b   = (bf16*) alloc((size_t)D_MODEL * D_INNER * 2);          //   4.2 MB
    float* hbuf  = (float*)alloc((size_t)NB * NCH * 128 * D_INNER * 4);   //  33.5 MB
    float* dts   = (float*)alloc((size_t)BT * 4);
    float* cumdt = (float*)alloc((size_t)BT * 4);
    // total ~256.0 MB (PROVEN).  Guarded.
    if (ws_size < off) return;

    // Aliases (lifetime-disjoint):
    bf16* whi = (bf16*)hbuf;                      // [split_w -> gemm1]; hbuf written by scan_local
    bf16* wlo = whi + (size_t)NCOLS * D_MODEL;
    bf16* xhi = (bf16*)d_out;                     // [split_x -> gemm1]
    bf16* xlo = xhi + (size_t)BT * D_MODEL;
    bf16* ybuf = (bf16*)d_out;                    // [scan_local -> rms_z], then gemm2 writes out
    bf16* hinH = (bf16*)xm;                       // [comb -> corr]; xm dead after scan_local
    bf16* hinL = hinH + (size_t)NB * NCH * D_INNER * 128;
    bf16* cmod = hinL + (size_t)NB * NCH * D_INNER * 128;   // 4.2 MB, still inside xm

    split_kernel<<<BT*D_MODEL/4/256, 256, 0, stream>>>(x, xhi, xlo, BT*D_MODEL/4);
    split_kernel<<<NCOLS*D_MODEL/4/256, 256, 0, stream>>>(in_w, whi, wlo, NCOLS*D_MODEL/4);
    cast_kernel<<<D_MODEL*D_INNER/4/256, 256, 0, stream>>>(out_w, w2b, D_MODEL*D_INNER/4);

    gemm1_split<<<dim3(BT/128, NCOLS/128), 256, 0, stream>>>(xhi, xlo, whi, wlo, zg, xm, bcbuf);
    dt_gemv<<<BT/4, 256, 0, stream>>>(x, in_w + (long)NCOLS * D_MODEL, dts);
    cumsum_chunks<<<NB*NCH, LCH, 0, stream>>>(dts, cumdt);
    scan_local<<<dim3(D_INNER/64, NCH, NB), 256, 0, stream>>>(dts, bcbuf, A_log, xm, conv_w, Dp, ybuf, hbuf);
    scan_comb<<<NB*128*D_INNER/256, 256, 0, stream>>>(hbuf, cumdt, A_log, hinH, hinL, hT);
    cmod_build<<<BT*128/256, 256, 0, stream>>>(cumdt, bcbuf, A_log, cmod);
    corr_gemm<<<dim3(BT/128, D_INNER/128), 256, 0, stream>>>(cmod, hinH, hinL, ybuf);
    rms_z<<<BT, 256, 0, stream>>>(ybuf, zg, norm_w);
    gemm2_mfma<<<dim3(BT/128, D_MODEL/128), 256, 0, stream>>>(zg, w2b, out);
}

// Round 19
// 1052.110 us; speedup vs baseline: 1.2955x; 1.0734x over previous
//
#include <hip/hip_runtime.h>
#include <hip/hip_bf16.h>
#include <math.h>
#include <stdint.h>

#define D_MODEL 1024
#define D_STATE 128
#define D_INNER 2048
#define NCOLS   4352     // z(2048) + xm(2048) + B(128) + C(128); dt row handled separately
#define NB      4
#define TLEN    4096
#define BT      16384    // NB*TLEN
#define LCH     512      // chunk length
#define NCH     8        // TLEN/LCH

using bf16 = __hip_bfloat16;
typedef __attribute__((ext_vector_type(2))) float f32x2;
typedef __attribute__((ext_vector_type(4))) float f32x4;
typedef __attribute__((ext_vector_type(8))) short short8x;

// fast clipped-silu: v_exp + v_rcp (~1e-7 rel).  Additive paths only.
__device__ __forceinline__ float csilu_fast(float v) {
    float e = __expf(-v);
    float s = v * __builtin_amdgcn_rcpf(1.f + e);
    return fminf(s, 8.f);
}

__device__ __forceinline__ void gload_lds16(const void* g, void* l) {
    __builtin_amdgcn_global_load_lds(
        (const __attribute__((address_space(1))) void*)g,
        (__attribute__((address_space(3))) void*)l, 16, 0, 0);
}

// ---------------- f32 -> bf16 cast ----------------
__global__ __launch_bounds__(256) void cast_kernel(const float* __restrict__ src,
                                                   bf16* __restrict__ dst, int n4) {
    int i = blockIdx.x * 256 + threadIdx.x;
    if (i < n4) {
        float4 v = ((const float4*)src)[i];
        dst[i*4+0] = __float2bfloat16(v.x);
        dst[i*4+1] = __float2bfloat16(v.y);
        dst[i*4+2] = __float2bfloat16(v.z);
        dst[i*4+3] = __float2bfloat16(v.w);
    }
}

// ---------------- f32 -> (hi, lo) bf16 split ----------------
__global__ __launch_bounds__(256) void split_kernel(const float* __restrict__ src,
                                                    bf16* __restrict__ hi,
                                                    bf16* __restrict__ lo, int n4) {
    int i = blockIdx.x * 256 + threadIdx.x;
    if (i < n4) {
        float4 v = ((const float4*)src)[i];
        #pragma unroll
        for (int j = 0; j < 4; ++j) {
            float f = (&v.x)[j];
            bf16 h = __float2bfloat16(f);
            hi[i*4+j] = h;
            lo[i*4+j] = __float2bfloat16(f - __bfloat162float(h));
        }
    }
}

// ---------------- GEMM1 split-bf16 MFMA: zxbcdt = x @ in_w^T ----------------
__global__ __launch_bounds__(256) void gemm1_split(const bf16* __restrict__ Ah,
                                                   const bf16* __restrict__ Al,
                                                   const bf16* __restrict__ Bh,
                                                   const bf16* __restrict__ Bl,
                                                   bf16* __restrict__ zdst,
                                                   float* __restrict__ xmdst,
                                                   float* __restrict__ bcdst) {
    const int K = D_MODEL;
    __shared__ __align__(16) bf16 sAh[128*32], sAl[128*32];
    __shared__ __align__(16) bf16 sBh[128*32], sBl[128*32];
    const int tid  = threadIdx.x;
    const int lane = tid & 63;
    const int wave = tid >> 6;
    const int wr   = (wave >> 1) * 64;
    const int wc   = (wave & 1) * 64;
    const long arow0 = (long)blockIdx.x * 128;
    const long brow0 = (long)blockIdx.y * 128;
    const long kb = (long)K * 2;
    const bool prec = (blockIdx.y >= 16);
    const char* gAh = (const char*)Ah;
    const char* gAl = (const char*)Al;
    const char* gBh = (const char*)Bh;
    const char* gBl = (const char*)Bl;

    f32x4 acc[4][4] = {};
    const int c1 = tid, c2 = tid + 256;
    const long aoff1 = (arow0 + (c1 >> 2)) * kb + (c1 & 3) * 16;
    const long aoff2 = (arow0 + (c2 >> 2)) * kb + (c2 & 3) * 16;
    const long boff1 = (brow0 + (c1 >> 2)) * kb + (c1 & 3) * 16;
    const long boff2 = (brow0 + (c2 >> 2)) * kb + (c2 & 3) * 16;

    for (int k0 = 0; k0 < K; k0 += 32) {
        __syncthreads();
        const long kk = (long)k0 * 2;
        gload_lds16(gAh + aoff1 + kk, (char*)sAh + c1*16);
        gload_lds16(gAh + aoff2 + kk, (char*)sAh + c2*16);
        gload_lds16(gBh + boff1 + kk, (char*)sBh + c1*16);
        gload_lds16(gBh + boff2 + kk, (char*)sBh + c2*16);
        if (prec) {
            gload_lds16(gAl + aoff1 + kk, (char*)sAl + c1*16);
            gload_lds16(gAl + aoff2 + kk, (char*)sAl + c2*16);
            gload_lds16(gBl + boff1 + kk, (char*)sBl + c1*16);
            gload_lds16(gBl + boff2 + kk, (char*)sBl + c2*16);
        }
        __syncthreads();

        const int r    = lane & 15;
        const int koff = (lane >> 4) * 8;
        short8x ah[4], bh[4];
        #pragma unroll
        for (int m = 0; m < 4; ++m)
            ah[m] = *(const short8x*)(sAh + (wr + m*16 + r) * 32 + koff);
        #pragma unroll
        for (int n = 0; n < 4; ++n)
            bh[n] = *(const short8x*)(sBh + (wc + n*16 + r) * 32 + koff);
        if (prec) {
            short8x al[4], bl[4];
            #pragma unroll
            for (int m = 0; m < 4; ++m)
                al[m] = *(const short8x*)(sAl + (wr + m*16 + r) * 32 + koff);
            #pragma unroll
            for (int n = 0; n < 4; ++n)
                bl[n] = *(const short8x*)(sBl + (wc + n*16 + r) * 32 + koff);
            #pragma unroll
            for (int m = 0; m < 4; ++m)
                #pragma unroll
                for (int n = 0; n < 4; ++n) {
                    acc[m][n] = __builtin_amdgcn_mfma_f32_16x16x32_bf16(ah[m], bh[n], acc[m][n], 0, 0, 0);
                    acc[m][n] = __builtin_amdgcn_mfma_f32_16x16x32_bf16(ah[m], bl[n], acc[m][n], 0, 0, 0);
                    acc[m][n] = __builtin_amdgcn_mfma_f32_16x16x32_bf16(al[m], bh[n], acc[m][n], 0, 0, 0);
                }
        } else {
            #pragma unroll
            for (int m = 0; m < 4; ++m)
                #pragma unroll
                for (int n = 0; n < 4; ++n)
                    acc[m][n] = __builtin_amdgcn_mfma_f32_16x16x32_bf16(ah[m], bh[n], acc[m][n], 0, 0, 0);
        }
    }

    const int r4 = (lane >> 4) * 4;
    const int cl = lane & 15;
    if (blockIdx.y < 16) {
        #pragma unroll
        for (int m = 0; m < 4; ++m)
            #pragma unroll
            for (int n = 0; n < 4; ++n) {
                const long row = arow0 + wr + m*16 + r4;
                const long col = brow0 + wc + n*16 + cl;
                #pragma unroll
                for (int j = 0; j < 4; ++j)
                    zdst[(row + j) * 2048 + col] = __float2bfloat16(acc[m][n][j]);
            }
    } else if (blockIdx.y < 32) {
        #pragma unroll
        for (int m = 0; m < 4; ++m)
            #pragma unroll
            for (int n = 0; n < 4; ++n) {
                const long row = arow0 + wr + m*16 + r4;
                const long col = brow0 - 2048 + wc + n*16 + cl;
                #pragma unroll
                for (int j = 0; j < 4; ++j)
                    xmdst[(row + j) * 2048 + col] = acc[m][n][j];
            }
    } else {
        #pragma unroll
        for (int m = 0; m < 4; ++m)
            #pragma unroll
            for (int n = 0; n < 4; ++n) {
                const long row = arow0 + wr + m*16 + r4;
                const long col = brow0 - 4096 + wc + n*16 + cl;
                #pragma unroll
                for (int j = 0; j < 4; ++j)
                    bcdst[(row + j) * 256 + col] = acc[m][n][j];
            }
    }
}

// ---------------- GEMM2 (m97 MFMA): out = ygated(bf16) @ w2b(bf16)^T ----------------
__global__ __launch_bounds__(256) void gemm2_mfma(const bf16* __restrict__ A,
                                                  const bf16* __restrict__ B,
                                                  float* __restrict__ C) {
    const int K = D_INNER;
    __shared__ __align__(16) bf16 sA[128*32];
    __shared__ __align__(16) bf16 sB[128*32];
    const int tid  = threadIdx.x;
    const int lane = tid & 63;
    const int wave = tid >> 6;
    const int wr   = (wave >> 1) * 64;
    const int wc   = (wave & 1) * 64;
    const long arow0 = (long)blockIdx.x * 128;
    const long brow0 = (long)blockIdx.y * 128;
    const long kb = (long)K * 2;
    const char* gA = (const char*)A;
    const char* gB = (const char*)B;

    f32x4 acc[4][4] = {};
    const int c1 = tid, c2 = tid + 256;
    for (int k0 = 0; k0 < K; k0 += 32) {
        __syncthreads();
        gload_lds16(gA + (arow0 + (c1 >> 2)) * kb + k0*2 + (c1 & 3) * 16, (char*)sA + c1*16);
        gload_lds16(gA + (arow0 + (c2 >> 2)) * kb + k0*2 + (c2 & 3) * 16, (char*)sA + c2*16);
        gload_lds16(gB + (brow0 + (c1 >> 2)) * kb + k0*2 + (c1 & 3) * 16, (char*)sB + c1*16);
        gload_lds16(gB + (brow0 + (c2 >> 2)) * kb + k0*2 + (c2 & 3) * 16, (char*)sB + c2*16);
        __syncthreads();

        const int r    = lane & 15;
        const int koff = (lane >> 4) * 8;
        short8x af[4], bfr[4];
        #pragma unroll
        for (int m = 0; m < 4; ++m)
            af[m] = *(const short8x*)(sA + (wr + m*16 + r) * 32 + koff);
        #pragma unroll
        for (int n = 0; n < 4; ++n)
            bfr[n] = *(const short8x*)(sB + (wc + n*16 + r) * 32 + koff);
        #pragma unroll
        for (int m = 0; m < 4; ++m)
            #pragma unroll
            for (int n = 0; n < 4; ++n)
                acc[m][n] = __builtin_amdgcn_mfma_f32_16x16x32_bf16(af[m], bfr[n], acc[m][n], 0, 0, 0);
    }

    const int r4 = (lane >> 4) * 4;
    const int cl = lane & 15;
    #pragma unroll
    for (int m = 0; m < 4; ++m) {
        #pragma unroll
        for (int n = 0; n < 4; ++n) {
            const long row = arow0 + wr + m*16 + r4;
            const long col = brow0 + wc + n*16 + cl;
            #pragma unroll
            for (int j = 0; j < 4; ++j)
                C[(row + j) * D_MODEL + col] = acc[m][n][j];
        }
    }
}

// ---------------- dt column in fp32 + softplus (accurate) ----------------
__global__ __launch_bounds__(256) void dt_gemv(const float* __restrict__ x,
                                               const float* __restrict__ wdt,
                                               float* __restrict__ dts) {
    const int row  = blockIdx.x * 4 + (threadIdx.x >> 6);
    const int lane = threadIdx.x & 63;
    const float4* xr = (const float4*)(x + (long)row * D_MODEL);
    const float4* wr = (const float4*)wdt;
    float acc = 0.f;
    for (int i = lane; i < D_MODEL/4; i += 64) {
        float4 a = xr[i], b = wr[i];
        acc += a.x*b.x + a.y*b.y + a.z*b.z + a.w*b.w;
    }
    for (int o = 32; o > 0; o >>= 1) acc += __shfl_down(acc, o);
    if (lane == 0)
        dts[row] = fmaxf(acc, 0.f) + log1pf(expf(-fabsf(acc)));
}

// ---------------- per-chunk (LCH=512) inclusive cumsum of dts ----------------
__global__ __launch_bounds__(LCH) void cumsum_chunks(const float* __restrict__ dts,
                                                     float* __restrict__ cumdt) {
    __shared__ float s[LCH];
    const int t = threadIdx.x;
    const long base = (long)blockIdx.x * LCH;
    s[t] = dts[base + t];
    __syncthreads();
    for (int o = 1; o < LCH; o <<= 1) {
        float v = (t >= o) ? s[t - o] : 0.f;
        __syncthreads();
        s[t] += v;
        __syncthreads();
    }
    cumdt[base + t] = s[t];
}

// ---------------- phase A: scan + fused conv4, 2 channels/lane + register prefetch ----------------
// Wave q owns states [32q,32q+32); per-wave staging (no barrier); 1 barrier/tile.
// Each lane handles d0=blk*128+dl and d1=d0+64: every sa/sb/sc LDS read feeds BOTH
// channels' pk-chains (LDS reads per channel halved, 2x ILP).  bc/dts/xm for tile
// t+1 prefetched into registers during tile t's compute (global latency hidden).
__global__ __launch_bounds__(256) void scan_local(const float* __restrict__ dts,
                                                  const float* __restrict__ bc,
                                                  const float* __restrict__ A_log,
                                                  const float* __restrict__ xm,
                                                  const float* __restrict__ cw,
                                                  const float* __restrict__ Dp,
                                                  bf16* __restrict__ ybuf,
                                                  float* __restrict__ hbuf) {
    const int tid = threadIdx.x;
    const int dl  = tid & 63;           // lane within wave
    const int q   = tid >> 6;           // wave id = s-quarter
    const int d0  = blockIdx.x * 128 + dl;
    const int d1  = d0 + 64;
    const int ch  = blockIdx.y;
    const int b   = blockIdx.z;
    const long row0 = (long)b * TLEN + ch * LCH;
    const int s0   = q * 32;
    const int scol = dl & 31;
    const int half = dl >> 5;
    const int sg   = s0 + scol;
    const float As_l = -expf(A_log[sg]);

    const float w00 = cw[d0*4+0], w01 = cw[d0*4+1], w02 = cw[d0*4+2], w03 = cw[d0*4+3];
    const float w10 = cw[d1*4+0], w11 = cw[d1*4+1], w12 = cw[d1*4+2], w13 = cw[d1*4+3];
    const float dpv0 = Dp[d0], dpv1 = Dp[d1];

    float p00 = 0.f, p01 = 0.f, p02 = 0.f;   // conv window channel d0
    float p10 = 0.f, p11 = 0.f, p12 = 0.f;   // conv window channel d1
    if (ch != 0) {
        p00 = csilu_fast(xm[(row0 - 3) * 2048 + d0]);
        p01 = csilu_fast(xm[(row0 - 2) * 2048 + d0]);
        p02 = csilu_fast(xm[(row0 - 1) * 2048 + d0]);
        p10 = csilu_fast(xm[(row0 - 3) * 2048 + d1]);
        p11 = csilu_fast(xm[(row0 - 2) * 2048 + d1]);
        p12 = csilu_fast(xm[(row0 - 1) * 2048 + d1]);
    }

    f32x2 hA[16], hB[16];                    // states for d0, d1
    #pragma unroll
    for (int k = 0; k < 16; ++k) { hA[k] = (f32x2){0.f,0.f}; hB[k] = (f32x2){0.f,0.f}; }

    __shared__ __align__(16) float sa[8][128], sb[8][128], sc[8][128];   // 12 KB
    __shared__ __align__(16) f32x2 yred[2][8][4][64];                    // 32 KB, parity
    int pbuf = 0;

    // prologue: prefetch tile 0
    float pfDT[4], pfB[4], pfC[4], pfXM0[8], pfXM1[8];
    #pragma unroll
    for (int k = 0; k < 4; ++k) {
        const long row = row0 + half + k*2;
        pfDT[k] = dts[row];
        pfB[k]  = bc[row*256 + sg];
        pfC[k]  = bc[row*256 + 128 + sg];
    }
    #pragma unroll
    for (int r = 0; r < 8; ++r) {
        pfXM0[r] = xm[(row0 + r) * 2048 + d0];
        pfXM1[r] = xm[(row0 + r) * 2048 + d1];
    }

    for (int tt = 0; tt < LCH; tt += 8) {
        // stage current tile from registers (no global on critical path)
        #pragma unroll
        for (int k = 0; k < 4; ++k) {
            const int r = half + k*2;
            sa[r][sg] = __expf(As_l * pfDT[k]);
            sb[r][sg] = pfB[k] * pfDT[k];       // B_bar
            sc[r][sg] = pfC[k];                 // raw C
        }
        float curXM0[8], curXM1[8];
        #pragma unroll
        for (int r = 0; r < 8; ++r) { curXM0[r] = pfXM0[r]; curXM1[r] = pfXM1[r]; }
        // issue next tile's loads (in flight under the compute below)
        if (tt + 8 < LCH) {
            #pragma unroll
            for (int k = 0; k < 4; ++k) {
                const long row = row0 + tt + 8 + half + k*2;
                pfDT[k] = dts[row];
                pfB[k]  = bc[row*256 + sg];
                pfC[k]  = bc[row*256 + 128 + sg];
            }
            #pragma unroll
            for (int r = 0; r < 8; ++r) {
                pfXM0[r] = xm[(row0 + tt + 8 + r) * 2048 + d0];
                pfXM1[r] = xm[(row0 + tt + 8 + r) * 2048 + d1];
            }
        }
        #pragma unroll
        for (int r = 0; r < 8; ++r) {
            const float cur0 = csilu_fast(curXM0[r]);
            const float cur1 = csilu_fast(curXM1[r]);
            const float xc0  = csilu_fast(w00*p00 + w01*p01 + w02*p02 + w03*cur0);
            const float xc1  = csilu_fast(w10*p10 + w11*p11 + w12*p12 + w13*cur1);
            p00 = p01; p01 = p02; p02 = cur0;
            p10 = p11; p11 = p12; p12 = cur1;
            const f32x2 x0 = (f32x2){xc0, xc0};
            const f32x2 x1 = (f32x2){xc1, xc1};
            f32x2 yA0 = {0.f,0.f}, yB0 = {0.f,0.f};
            f32x2 yA1 = {0.f,0.f}, yB1 = {0.f,0.f};
            #pragma unroll
            for (int k = 0; k < 8; ++k) {            // 4 states/iter, both channels
                const f32x4 a4 = *(const f32x4*)&sa[r][s0 + k*4];
                const f32x4 b4 = *(const f32x4*)&sb[r][s0 + k*4];
                const f32x4 c4 = *(const f32x4*)&sc[r][s0 + k*4];
                const f32x2 aL = {a4.x, a4.y}, aH = {a4.z, a4.w};
                const f32x2 bL = {b4.x, b4.y}, bH = {b4.z, b4.w};
                const f32x2 cL = {c4.x, c4.y}, cH = {c4.z, c4.w};
                hA[k*2+0] = aL * hA[k*2+0] + bL * x0;
                hA[k*2+1] = aH * hA[k*2+1] + bH * x0;
                hB[k*2+0] = aL * hB[k*2+0] + bL * x1;
                hB[k*2+1] = aH * hB[k*2+1] + bH * x1;
                yA0 = hA[k*2+0] * cL + yA0;
                yB0 = hA[k*2+1] * cH + yB0;
                yA1 = hB[k*2+0] * cL + yA1;
                yB1 = hB[k*2+1] * cH + yB1;
            }
            f32x2 ypair;
            ypair.x = (yA0.x + yA0.y) + (yB0.x + yB0.y) + (q == 0 ? dpv0 * xc0 : 0.f);
            ypair.y = (yA1.x + yA1.y) + (yB1.x + yB1.y) + (q == 0 ? dpv1 * xc1 : 0.f);
            yred[pbuf][r][q][dl] = ypair;
        }
        __syncthreads();                         // all waves' yred[pbuf] writes visible
        #pragma unroll
        for (int i2 = 0; i2 < 4; ++i2) {         // 8 rows x 128 ch = 1024 outputs / 256 thr
            const int i = tid + i2 * 256;
            const int r = i >> 7, c = i & 127;
            const int cl2 = c & 63;
            float y = 0.f;
            if (c < 64) {
                #pragma unroll
                for (int q2 = 0; q2 < 4; ++q2) y += yred[pbuf][r][q2][cl2].x;
            } else {
                #pragma unroll
                for (int q2 = 0; q2 < 4; ++q2) y += yred[pbuf][r][q2][cl2].y;
            }
            ybuf[(row0 + tt + r) * 2048 + blockIdx.x * 128 + c] = __float2bfloat16(y);
        }
        pbuf ^= 1;                               // parity: no second barrier
    }
    // chunk-final h, transposed layout [d][s]
    const long hb0 = ((long)(b * NCH + ch) * 2048 + d0) * 128;
    const long hb1 = ((long)(b * NCH + ch) * 2048 + d1) * 128;
    #pragma unroll
    for (int k = 0; k < 8; ++k) {
        *(float4*)&hbuf[hb0 + s0 + k*4] = make_float4(hA[k*2].x, hA[k*2].y, hA[k*2+1].x, hA[k*2+1].y);
        *(float4*)&hbuf[hb1 + s0 + k*4] = make_float4(hB[k*2].x, hB[k*2].y, hB[k*2+1].x, hB[k*2+1].y);
    }
}

// ---------------- phase B: cross-chunk combine; h_in -> hi/lo bf16 (transposed) + hT ----------------
__global__ __launch_bounds__(256) void scan_comb(const float* __restrict__ hbuf,
                                                 const float* __restrict__ cumdt,
                                                 const float* __restrict__ A_log,
                                                 bf16* __restrict__ hinH,
                                                 bf16* __restrict__ hinL,
                                                 float* __restrict__ hT) {
    const long idx = (long)blockIdx.x * 256 + threadIdx.x;   // over B*D*S, s fastest
    const int s = (int)(idx & 127);
    const int d = (int)((idx >> 7) & 2047);
    const int b = (int)(idx >> 18);
    const float As = -expf(A_log[s]);
    float hr = 0.f;
    for (int c = 0; c < NCH; ++c) {
        const long off = ((long)(b * NCH + c) * 2048 + d) * 128 + s;
        const float loc = hbuf[off];
        const bf16 hh = __float2bfloat16(hr);
        hinH[off] = hh;
        hinL[off] = __float2bfloat16(hr - __bfloat162float(hh));
        const float p = __expf(As * cumdt[(long)b * TLEN + c * LCH + (LCH - 1)]);
        hr = p * hr + loc;
    }
    hT[((long)b * 2048 + d) * 128 + s] = hr;
}

// ---------------- Cmod precompute: cmod[row,s] = C[row,s] * exp(As*cumdt[row]) (bf16) ----------------
__global__ __launch_bounds__(256) void cmod_build(const float* __restrict__ cumdt,
                                                  const float* __restrict__ bc,
                                                  const float* __restrict__ A_log,
                                                  bf16* __restrict__ cmod) {
    const long i = (long)blockIdx.x * 256 + threadIdx.x;   // over BT*128
    const int s = (int)(i & 127);
    const long row = i >> 7;
    const float As = -__expf(A_log[s]);
    cmod[i] = __float2bfloat16(bc[row*256 + 128 + s] * __expf(As * cumdt[row]));
}

// ---------------- phase C as GEMM: Y += Cmod(512x128) @ Hin(128x2048) per (b,ch) ----------------
__global__ __launch_bounds__(256) void corr_gemm(const bf16* __restrict__ cmod,
                                                 const bf16* __restrict__ hinH,
                                                 const bf16* __restrict__ hinL,
                                                 bf16* __restrict__ ybuf) {
    __shared__ __align__(16) bf16 sA[128*32];
    __shared__ __align__(16) bf16 sBh[128*32], sBl[128*32];
    const int tid  = threadIdx.x;
    const int lane = tid & 63;
    const int wave = tid >> 6;
    const int wr   = (wave >> 1) * 64;
    const int wc   = (wave & 1) * 64;
    const long arow0 = (long)blockIdx.x * 128;      // rows over BT (within one 512-chunk)
    const long bcol0 = (long)blockIdx.y * 128;      // channels
    const int b  = (int)(arow0 >> 12);
    const int ch = (int)((arow0 & 4095) >> 9);
    const char* gA = (const char*)cmod;             // [BT][128] bf16, 256 B rows
    const char* gH = (const char*)(hinH + (long)(b * NCH + ch) * 2048 * 128);
    const char* gL = (const char*)(hinL + (long)(b * NCH + ch) * 2048 * 128);

    f32x4 acc[4][4] = {};
    const int c1 = tid, c2 = tid + 256;
    for (int k0 = 0; k0 < 128; k0 += 32) {
        __syncthreads();
        gload_lds16(gA + (arow0 + (c1 >> 2))*256 + k0*2 + (c1 & 3)*16, (char*)sA + c1*16);
        gload_lds16(gA + (arow0 + (c2 >> 2))*256 + k0*2 + (c2 & 3)*16, (char*)sA + c2*16);
        gload_lds16(gH + (bcol0 + (c1 >> 2))*256 + k0*2 + (c1 & 3)*16, (char*)sBh + c1*16);
        gload_lds16(gH + (bcol0 + (c2 >> 2))*256 + k0*2 + (c2 & 3)*16, (char*)sBh + c2*16);
        gload_lds16(gL + (bcol0 + (c1 >> 2))*256 + k0*2 + (c1 & 3)*16, (char*)sBl + c1*16);
        gload_lds16(gL + (bcol0 + (c2 >> 2))*256 + k0*2 + (c2 & 3)*16, (char*)sBl + c2*16);
        __syncthreads();

        const int r    = lane & 15;
        const int koff = (lane >> 4) * 8;
        short8x af[4], bh[4], bl[4];
        #pragma unroll
        for (int m = 0; m < 4; ++m)
            af[m] = *(const short8x*)(sA + (wr + m*16 + r) * 32 + koff);
        #pragma unroll
        for (int n = 0; n < 4; ++n) {
            bh[n] = *(const short8x*)(sBh + (wc + n*16 + r) * 32 + koff);
            bl[n] = *(const short8x*)(sBl + (wc + n*16 + r) * 32 + koff);
        }
        #pragma unroll
        for (int m = 0; m < 4; ++m)
            #pragma unroll
            for (int n = 0; n < 4; ++n) {
                acc[m][n] = __builtin_amdgcn_mfma_f32_16x16x32_bf16(af[m], bh[n], acc[m][n], 0, 0, 0);
                acc[m][n] = __builtin_amdgcn_mfma_f32_16x16x32_bf16(af[m], bl[n], acc[m][n], 0, 0, 0);
            }
    }

    const int r4 = (lane >> 4) * 4;
    const int cl = lane & 15;
    #pragma unroll
    for (int m = 0; m < 4; ++m) {
        #pragma unroll
        for (int n = 0; n < 4; ++n) {
            const long row = arow0 + wr + m*16 + r4;
            const long col = bcol0 + wc + n*16 + cl;
            #pragma unroll
            for (int j = 0; j < 4; ++j) {
                const long o = (row + j) * 2048 + col;
                ybuf[o] = __float2bfloat16(__bfloat162float(ybuf[o]) + acc[m][n][j]);
            }
        }
    }
}

// ---------------- RMSNorm * norm_w * csilu(z): ygated bf16 written over z ----------------
__global__ __launch_bounds__(256) void rms_z(const bf16* __restrict__ ybuf,
                                             bf16* __restrict__ zg,
                                             const float* __restrict__ norm_w) {
    const long row = blockIdx.x;
    const int tid = threadIdx.x;
    float v[8];
    float ss = 0.f;
    #pragma unroll
    for (int i = 0; i < 8; ++i) {
        v[i] = __bfloat162float(ybuf[row * D_INNER + i*256 + tid]);
        ss += v[i] * v[i];
    }
    __shared__ float red[256];
    red[tid] = ss;
    __syncthreads();
    for (int o = 128; o > 0; o >>= 1) {
        if (tid < o) red[tid] += red[tid + o];
        __syncthreads();
    }
    const float scale = rsqrtf(red[0] * (1.f / D_INNER) + 1e-5f);
    #pragma unroll
    for (int i = 0; i < 8; ++i) {
        const int dd = i*256 + tid;
        const float z = __bfloat162float(zg[row * D_INNER + dd]);
        zg[row * D_INNER + dd] = __float2bfloat16(v[i] * scale * norm_w[dd] * csilu_fast(z));
    }
}

extern "C" void kernel_launch(void* const* d_in, const int* in_sizes, int n_in,
                              void* d_out, int out_size, void* d_ws, size_t ws_size,
                              hipStream_t stream) {
    const float* x      = (const float*)d_in[0];
    const float* in_w   = (const float*)d_in[1];   // (4353, 1024)
    const float* conv_w = (const float*)d_in[2];   // (2048, 1, 4)
    const float* A_log  = (const float*)d_in[3];   // (128,)
    const float* Dp     = (const float*)d_in[4];   // (2048,)
    const float* norm_w = (const float*)d_in[5];   // (2048,)
    const float* out_w  = (const float*)d_in[6];   // (1024, 2048)
    float* out = (float*)d_out;
    float* hT  = out + (long)BT * D_MODEL;

    char* ws = (char*)d_ws;
    size_t off = 0;
    auto alloc = [&](size_t bytes) { void* p = ws + off; off += (bytes + 255) & ~(size_t)255; return p; };
    bf16*  zg    = (bf16*) alloc((size_t)BT * D_INNER * 2);               //  67.1 MB: z -> ygated
    float* xm    = (float*)alloc((size_t)BT * D_INNER * 4);               // 134.2 MB: xm f32
    float* bcbuf = (float*)alloc((size_t)BT * 256 * 4);                   //  16.8 MB: B|C f32
    bf16*  w2b   = (bf16*) alloc((size_t)D_MODEL * D_INNER * 2);          //   4.2 MB
    float* hbuf  = (float*)alloc((size_t)NB * NCH * 128 * D_INNER * 4);   //  33.5 MB
    float* dts   = (float*)alloc((size_t)BT * 4);
    float* cumdt = (float*)alloc((size_t)BT * 4);
    // total ~256.0 MB (PROVEN).  Guarded.
    if (ws_size < off) return;

    // Aliases (lifetime-disjoint):
    bf16* whi = (bf16*)hbuf;                      // [split_w -> gemm1]; hbuf written by scan_local
    bf16* wlo = whi + (size_t)NCOLS * D_MODEL;
    bf16* xhi = (bf16*)d_out;                     // [split_x -> gemm1]
    bf16* xlo = xhi + (size_t)BT * D_MODEL;
    bf16* ybuf = (bf16*)d_out;                    // [scan_local -> rms_z], then gemm2 writes out
    bf16* hinH = (bf16*)xm;                       // [comb -> corr]; xm dead after scan_local
    bf16* hinL = hinH + (size_t)NB * NCH * D_INNER * 128;
    bf16* cmod = hinL + (size_t)NB * NCH * D_INNER * 128;   // 4.2 MB, still inside xm

    split_kernel<<<BT*D_MODEL/4/256, 256, 0, stream>>>(x, xhi, xlo, BT*D_MODEL/4);
    split_kernel<<<NCOLS*D_MODEL/4/256, 256, 0, stream>>>(in_w, whi, wlo, NCOLS*D_MODEL/4);
    cast_kernel<<<D_MODEL*D_INNER/4/256, 256, 0, stream>>>(out_w, w2b, D_MODEL*D_INNER/4);

    gemm1_split<<<dim3(BT/128, NCOLS/128), 256, 0, stream>>>(xhi, xlo, whi, wlo, zg, xm, bcbuf);
    dt_gemv<<<BT/4, 256, 0, stream>>>(x, in_w + (long)NCOLS * D_MODEL, dts);
    cumsum_chunks<<<NB*NCH, LCH, 0, stream>>>(dts, cumdt);
    scan_local<<<dim3(D_INNER/128, NCH, NB), 256, 0, stream>>>(dts, bcbuf, A_log, xm, conv_w, Dp, ybuf, hbuf);
    scan_comb<<<NB*128*D_INNER/256, 256, 0, stream>>>(hbuf, cumdt, A_log, hinH, hinL, hT);
    cmod_build<<<BT*128/256, 256, 0, stream>>>(cumdt, bcbuf, A_log, cmod);
    corr_gemm<<<dim3(BT/128, D_INNER/128), 256, 0, stream>>>(cmod, hinH, hinL, ybuf);
    rms_z<<<BT, 256, 0, stream>>>(ybuf, zg, norm_w);
    gemm2_mfma<<<dim3(BT/128, D_MODEL/128), 256, 0, stream>>>(zg, w2b, out);
}

// Round 20
// 1002.506 us; speedup vs baseline: 1.3596x; 1.0495x over previous
//
#include <hip/hip_runtime.h>
#include <hip/hip_bf16.h>
#include <math.h>
#include <stdint.h>

#define D_MODEL 1024
#define D_STATE 128
#define D_INNER 2048
#define NCOLS   4352     // z(2048) + xm(2048) + B(128) + C(128); dt row handled separately
#define NB      4
#define TLEN    4096
#define BT      16384    // NB*TLEN
#define LCH     512      // chunk length
#define NCH     8        // TLEN/LCH

using bf16 = __hip_bfloat16;
typedef __attribute__((ext_vector_type(2))) float f32x2;
typedef __attribute__((ext_vector_type(4))) float f32x4;
typedef __attribute__((ext_vector_type(8))) short short8x;

// fast clipped-silu: v_exp + v_rcp (~1e-7 rel).  Additive paths only.
__device__ __forceinline__ float csilu_fast(float v) {
    float e = __expf(-v);
    float s = v * __builtin_amdgcn_rcpf(1.f + e);
    return fminf(s, 8.f);
}

__device__ __forceinline__ void gload_lds16(const void* g, void* l) {
    __builtin_amdgcn_global_load_lds(
        (const __attribute__((address_space(1))) void*)g,
        (__attribute__((address_space(3))) void*)l, 16, 0, 0);
}

// ---------------- f32 -> bf16 cast ----------------
__global__ __launch_bounds__(256) void cast_kernel(const float* __restrict__ src,
                                                   bf16* __restrict__ dst, int n4) {
    int i = blockIdx.x * 256 + threadIdx.x;
    if (i < n4) {
        float4 v = ((const float4*)src)[i];
        dst[i*4+0] = __float2bfloat16(v.x);
        dst[i*4+1] = __float2bfloat16(v.y);
        dst[i*4+2] = __float2bfloat16(v.z);
        dst[i*4+3] = __float2bfloat16(v.w);
    }
}

// ---------------- f32 -> (hi, lo) bf16 split ----------------
__global__ __launch_bounds__(256) void split_kernel(const float* __restrict__ src,
                                                    bf16* __restrict__ hi,
                                                    bf16* __restrict__ lo, int n4) {
    int i = blockIdx.x * 256 + threadIdx.x;
    if (i < n4) {
        float4 v = ((const float4*)src)[i];
        #pragma unroll
        for (int j = 0; j < 4; ++j) {
            float f = (&v.x)[j];
            bf16 h = __float2bfloat16(f);
            hi[i*4+j] = h;
            lo[i*4+j] = __float2bfloat16(f - __bfloat162float(h));
        }
    }
}

// ---------------- GEMM1 split-bf16 MFMA: zxbcdt = x @ in_w^T ----------------
__global__ __launch_bounds__(256) void gemm1_split(const bf16* __restrict__ Ah,
                                                   const bf16* __restrict__ Al,
                                                   const bf16* __restrict__ Bh,
                                                   const bf16* __restrict__ Bl,
                                                   bf16* __restrict__ zdst,
                                                   float* __restrict__ xmdst,
                                                   float* __restrict__ bcdst) {
    const int K = D_MODEL;
    __shared__ __align__(16) bf16 sAh[128*32], sAl[128*32];
    __shared__ __align__(16) bf16 sBh[128*32], sBl[128*32];
    const int tid  = threadIdx.x;
    const int lane = tid & 63;
    const int wave = tid >> 6;
    const int wr   = (wave >> 1) * 64;
    const int wc   = (wave & 1) * 64;
    const long arow0 = (long)blockIdx.x * 128;
    const long brow0 = (long)blockIdx.y * 128;
    const long kb = (long)K * 2;
    const bool prec = (blockIdx.y >= 16);
    const char* gAh = (const char*)Ah;
    const char* gAl = (const char*)Al;
    const char* gBh = (const char*)Bh;
    const char* gBl = (const char*)Bl;

    f32x4 acc[4][4] = {};
    const int c1 = tid, c2 = tid + 256;
    const long aoff1 = (arow0 + (c1 >> 2)) * kb + (c1 & 3) * 16;
    const long aoff2 = (arow0 + (c2 >> 2)) * kb + (c2 & 3) * 16;
    const long boff1 = (brow0 + (c1 >> 2)) * kb + (c1 & 3) * 16;
    const long boff2 = (brow0 + (c2 >> 2)) * kb + (c2 & 3) * 16;

    for (int k0 = 0; k0 < K; k0 += 32) {
        __syncthreads();
        const long kk = (long)k0 * 2;
        gload_lds16(gAh + aoff1 + kk, (char*)sAh + c1*16);
        gload_lds16(gAh + aoff2 + kk, (char*)sAh + c2*16);
        gload_lds16(gBh + boff1 + kk, (char*)sBh + c1*16);
        gload_lds16(gBh + boff2 + kk, (char*)sBh + c2*16);
        if (prec) {
            gload_lds16(gAl + aoff1 + kk, (char*)sAl + c1*16);
            gload_lds16(gAl + aoff2 + kk, (char*)sAl + c2*16);
            gload_lds16(gBl + boff1 + kk, (char*)sBl + c1*16);
            gload_lds16(gBl + boff2 + kk, (char*)sBl + c2*16);
        }
        __syncthreads();

        const int r    = lane & 15;
        const int koff = (lane >> 4) * 8;
        short8x ah[4], bh[4];
        #pragma unroll
        for (int m = 0; m < 4; ++m)
            ah[m] = *(const short8x*)(sAh + (wr + m*16 + r) * 32 + koff);
        #pragma unroll
        for (int n = 0; n < 4; ++n)
            bh[n] = *(const short8x*)(sBh + (wc + n*16 + r) * 32 + koff);
        if (prec) {
            short8x al[4], bl[4];
            #pragma unroll
            for (int m = 0; m < 4; ++m)
                al[m] = *(const short8x*)(sAl + (wr + m*16 + r) * 32 + koff);
            #pragma unroll
            for (int n = 0; n < 4; ++n)
                bl[n] = *(const short8x*)(sBl + (wc + n*16 + r) * 32 + koff);
            #pragma unroll
            for (int m = 0; m < 4; ++m)
                #pragma unroll
                for (int n = 0; n < 4; ++n) {
                    acc[m][n] = __builtin_amdgcn_mfma_f32_16x16x32_bf16(ah[m], bh[n], acc[m][n], 0, 0, 0);
                    acc[m][n] = __builtin_amdgcn_mfma_f32_16x16x32_bf16(ah[m], bl[n], acc[m][n], 0, 0, 0);
                    acc[m][n] = __builtin_amdgcn_mfma_f32_16x16x32_bf16(al[m], bh[n], acc[m][n], 0, 0, 0);
                }
        } else {
            #pragma unroll
            for (int m = 0; m < 4; ++m)
                #pragma unroll
                for (int n = 0; n < 4; ++n)
                    acc[m][n] = __builtin_amdgcn_mfma_f32_16x16x32_bf16(ah[m], bh[n], acc[m][n], 0, 0, 0);
        }
    }

    const int r4 = (lane >> 4) * 4;
    const int cl = lane & 15;
    if (blockIdx.y < 16) {
        #pragma unroll
        for (int m = 0; m < 4; ++m)
            #pragma unroll
            for (int n = 0; n < 4; ++n) {
                const long row = arow0 + wr + m*16 + r4;
                const long col = brow0 + wc + n*16 + cl;
                #pragma unroll
                for (int j = 0; j < 4; ++j)
                    zdst[(row + j) * 2048 + col] = __float2bfloat16(acc[m][n][j]);
            }
    } else if (blockIdx.y < 32) {
        #pragma unroll
        for (int m = 0; m < 4; ++m)
            #pragma unroll
            for (int n = 0; n < 4; ++n) {
                const long row = arow0 + wr + m*16 + r4;
                const long col = brow0 - 2048 + wc + n*16 + cl;
                #pragma unroll
                for (int j = 0; j < 4; ++j)
                    xmdst[(row + j) * 2048 + col] = acc[m][n][j];
            }
    } else {
        #pragma unroll
        for (int m = 0; m < 4; ++m)
            #pragma unroll
            for (int n = 0; n < 4; ++n) {
                const long row = arow0 + wr + m*16 + r4;
                const long col = brow0 - 4096 + wc + n*16 + cl;
                #pragma unroll
                for (int j = 0; j < 4; ++j)
                    bcdst[(row + j) * 256 + col] = acc[m][n][j];
            }
    }
}

// ---------------- GEMM2 (m97 MFMA): out = ygated(bf16) @ w2b(bf16)^T ----------------
__global__ __launch_bounds__(256) void gemm2_mfma(const bf16* __restrict__ A,
                                                  const bf16* __restrict__ B,
                                                  float* __restrict__ C) {
    const int K = D_INNER;
    __shared__ __align__(16) bf16 sA[128*32];
    __shared__ __align__(16) bf16 sB[128*32];
    const int tid  = threadIdx.x;
    const int lane = tid & 63;
    const int wave = tid >> 6;
    const int wr   = (wave >> 1) * 64;
    const int wc   = (wave & 1) * 64;
    const long arow0 = (long)blockIdx.x * 128;
    const long brow0 = (long)blockIdx.y * 128;
    const long kb = (long)K * 2;
    const char* gA = (const char*)A;
    const char* gB = (const char*)B;

    f32x4 acc[4][4] = {};
    const int c1 = tid, c2 = tid + 256;
    for (int k0 = 0; k0 < K; k0 += 32) {
        __syncthreads();
        gload_lds16(gA + (arow0 + (c1 >> 2)) * kb + k0*2 + (c1 & 3) * 16, (char*)sA + c1*16);
        gload_lds16(gA + (arow0 + (c2 >> 2)) * kb + k0*2 + (c2 & 3) * 16, (char*)sA + c2*16);
        gload_lds16(gB + (brow0 + (c1 >> 2)) * kb + k0*2 + (c1 & 3) * 16, (char*)sB + c1*16);
        gload_lds16(gB + (brow0 + (c2 >> 2)) * kb + k0*2 + (c2 & 3) * 16, (char*)sB + c2*16);
        __syncthreads();

        const int r    = lane & 15;
        const int koff = (lane >> 4) * 8;
        short8x af[4], bfr[4];
        #pragma unroll
        for (int m = 0; m < 4; ++m)
            af[m] = *(const short8x*)(sA + (wr + m*16 + r) * 32 + koff);
        #pragma unroll
        for (int n = 0; n < 4; ++n)
            bfr[n] = *(const short8x*)(sB + (wc + n*16 + r) * 32 + koff);
        #pragma unroll
        for (int m = 0; m < 4; ++m)
            #pragma unroll
            for (int n = 0; n < 4; ++n)
                acc[m][n] = __builtin_amdgcn_mfma_f32_16x16x32_bf16(af[m], bfr[n], acc[m][n], 0, 0, 0);
    }

    const int r4 = (lane >> 4) * 4;
    const int cl = lane & 15;
    #pragma unroll
    for (int m = 0; m < 4; ++m) {
        #pragma unroll
        for (int n = 0; n < 4; ++n) {
            const long row = arow0 + wr + m*16 + r4;
            const long col = brow0 + wc + n*16 + cl;
            #pragma unroll
            for (int j = 0; j < 4; ++j)
                C[(row + j) * D_MODEL + col] = acc[m][n][j];
        }
    }
}

// ---------------- dt column in fp32 + softplus (accurate) ----------------
__global__ __launch_bounds__(256) void dt_gemv(const float* __restrict__ x,
                                               const float* __restrict__ wdt,
                                               float* __restrict__ dts) {
    const int row  = blockIdx.x * 4 + (threadIdx.x >> 6);
    const int lane = threadIdx.x & 63;
    const float4* xr = (const float4*)(x + (long)row * D_MODEL);
    const float4* wr = (const float4*)wdt;
    float acc = 0.f;
    for (int i = lane; i < D_MODEL/4; i += 64) {
        float4 a = xr[i], b = wr[i];
        acc += a.x*b.x + a.y*b.y + a.z*b.z + a.w*b.w;
    }
    for (int o = 32; o > 0; o >>= 1) acc += __shfl_down(acc, o);
    if (lane == 0)
        dts[row] = fmaxf(acc, 0.f) + log1pf(expf(-fabsf(acc)));
}

// ---------------- per-chunk (LCH=512) inclusive cumsum of dts ----------------
__global__ __launch_bounds__(LCH) void cumsum_chunks(const float* __restrict__ dts,
                                                     float* __restrict__ cumdt) {
    __shared__ float s[LCH];
    const int t = threadIdx.x;
    const long base = (long)blockIdx.x * LCH;
    s[t] = dts[base + t];
    __syncthreads();
    for (int o = 1; o < LCH; o <<= 1) {
        float v = (t >= o) ? s[t - o] : 0.f;
        __syncthreads();
        s[t] += v;
        __syncthreads();
    }
    cumdt[base + t] = s[t];
}

// ---------------- phase A: scan, 2 ch/lane + prefetch + DEDUP'd conv via LDS ----------------
// Conv is a stateless FIR: wave q computes xc only for tile-rows {2q,2q+1} (both
// channels) and publishes via parity-buffered sxc; all waves read xc with 2
// conflict-free b32 reads/row (kills the 4x-redundant conv/silu VALU).  Y-readout
// is software-pipelined one tile behind so the single barrier/tile is kept.
__global__ __launch_bounds__(256) void scan_local(const float* __restrict__ dts,
                                                  const float* __restrict__ bc,
                                                  const float* __restrict__ A_log,
                                                  const float* __restrict__ xm,
                                                  const float* __restrict__ cw,
                                                  const float* __restrict__ Dp,
                                                  bf16* __restrict__ ybuf,
                                                  float* __restrict__ hbuf) {
    const int tid = threadIdx.x;
    const int dl  = tid & 63;           // lane within wave
    const int q   = tid >> 6;           // wave id = s-quarter; also owns conv rows 2q,2q+1
    const int d0  = blockIdx.x * 128 + dl;
    const int d1  = d0 + 64;
    const int ch  = blockIdx.y;
    const int b   = blockIdx.z;
    const long row0 = (long)b * TLEN + ch * LCH;
    const int s0   = q * 32;
    const int scol = dl & 31;
    const int half = dl >> 5;
    const int sg   = s0 + scol;
    const float As_l = -expf(A_log[sg]);

    const float w00 = cw[d0*4+0], w01 = cw[d0*4+1], w02 = cw[d0*4+2], w03 = cw[d0*4+3];
    const float w10 = cw[d1*4+0], w11 = cw[d1*4+1], w12 = cw[d1*4+2], w13 = cw[d1*4+3];
    const float dpv0 = Dp[d0], dpv1 = Dp[d1];

    f32x2 hA[16], hB[16];                    // states for d0, d1
    #pragma unroll
    for (int k = 0; k < 16; ++k) { hA[k] = (f32x2){0.f,0.f}; hB[k] = (f32x2){0.f,0.f}; }

    __shared__ __align__(16) float sa[8][128], sb[8][128], sc[8][128];   // 12 KB
    __shared__ __align__(16) float sxc[2][8][128];                       //  8 KB, parity
    __shared__ __align__(16) f32x2 yred[2][8][4][64];                    // 32 KB, parity
    int pbuf = 0;

    // prologue: prefetch tile 0 (staging + 5 xm taps for conv rows 2q,2q+1)
    float pfDT[4], pfB[4], pfC[4], pfX0[5], pfX1[5];
    #pragma unroll
    for (int k = 0; k < 4; ++k) {
        const long row = row0 + half + k*2;
        pfDT[k] = dts[row];
        pfB[k]  = bc[row*256 + sg];
        pfC[k]  = bc[row*256 + 128 + sg];
    }
    #pragma unroll
    for (int j = 0; j < 5; ++j) {
        const int t = 2*q - 3 + j;                       // chunk-relative row
        const bool ok = (ch != 0) || (t >= 0);           // zero-pad at sequence start
        pfX0[j] = ok ? xm[(row0 + t) * 2048 + d0] : 0.f;
        pfX1[j] = ok ? xm[(row0 + t) * 2048 + d1] : 0.f;
    }

    for (int tt = 0; tt < LCH; tt += 8) {
        // stage decay/B/C from regs (own s-columns; within-wave, no barrier)
        #pragma unroll
        for (int k = 0; k < 4; ++k) {
            const int r = half + k*2;
            sa[r][sg] = __expf(As_l * pfDT[k]);
            sb[r][sg] = pfB[k] * pfDT[k];       // B_bar
            sc[r][sg] = pfC[k];                 // raw C
        }
        // conv for this wave's 2 rows (both channels) -> sxc[pbuf]
        {
            float px0[5], px1[5];
            #pragma unroll
            for (int j = 0; j < 5; ++j) { px0[j] = csilu_fast(pfX0[j]); px1[j] = csilu_fast(pfX1[j]); }
            sxc[pbuf][2*q+0][dl]      = csilu_fast(w00*px0[0] + w01*px0[1] + w02*px0[2] + w03*px0[3]);
            sxc[pbuf][2*q+1][dl]      = csilu_fast(w00*px0[1] + w01*px0[2] + w02*px0[3] + w03*px0[4]);
            sxc[pbuf][2*q+0][dl+64]   = csilu_fast(w10*px1[0] + w11*px1[1] + w12*px1[2] + w13*px1[3]);
            sxc[pbuf][2*q+1][dl+64]   = csilu_fast(w10*px1[1] + w11*px1[2] + w12*px1[3] + w13*px1[4]);
        }
        // issue next tile's loads (in flight under compute)
        if (tt + 8 < LCH) {
            #pragma unroll
            for (int k = 0; k < 4; ++k) {
                const long row = row0 + tt + 8 + half + k*2;
                pfDT[k] = dts[row];
                pfB[k]  = bc[row*256 + sg];
                pfC[k]  = bc[row*256 + 128 + sg];
            }
            const int tr = tt + 8 + 2*q;
            #pragma unroll
            for (int j = 0; j < 5; ++j) {
                pfX0[j] = xm[(row0 + tr - 3 + j) * 2048 + d0];   // tr-3 >= 5: always valid
                pfX1[j] = xm[(row0 + tr - 3 + j) * 2048 + d1];
            }
        }
        __syncthreads();                         // sxc[pbuf] + prev yred visible
        // pipelined readout of PREVIOUS tile's y
        if (tt > 0) {
            #pragma unroll
            for (int i2 = 0; i2 < 4; ++i2) {
                const int i = tid + i2 * 256;
                const int r = i >> 7, c = i & 127;
                const int cl2 = c & 63;
                float y = 0.f;
                if (c < 64) {
                    #pragma unroll
                    for (int q2 = 0; q2 < 4; ++q2) y += yred[pbuf^1][r][q2][cl2].x;
                } else {
                    #pragma unroll
                    for (int q2 = 0; q2 < 4; ++q2) y += yred[pbuf^1][r][q2][cl2].y;
                }
                ybuf[(row0 + (tt-8) + r) * 2048 + blockIdx.x * 128 + c] = __float2bfloat16(y);
            }
        }
        // compute 8 rows
        #pragma unroll
        for (int r = 0; r < 8; ++r) {
            const float xc0 = sxc[pbuf][r][dl];
            const float xc1 = sxc[pbuf][r][dl+64];
            const f32x2 x0 = (f32x2){xc0, xc0};
            const f32x2 x1 = (f32x2){xc1, xc1};
            f32x2 yA0 = {0.f,0.f}, yB0 = {0.f,0.f};
            f32x2 yA1 = {0.f,0.f}, yB1 = {0.f,0.f};
            #pragma unroll
            for (int k = 0; k < 8; ++k) {            // 4 states/iter, both channels
                const f32x4 a4 = *(const f32x4*)&sa[r][s0 + k*4];
                const f32x4 b4 = *(const f32x4*)&sb[r][s0 + k*4];
                const f32x4 c4 = *(const f32x4*)&sc[r][s0 + k*4];
                const f32x2 aL = {a4.x, a4.y}, aH = {a4.z, a4.w};
                const f32x2 bL = {b4.x, b4.y}, bH = {b4.z, b4.w};
                const f32x2 cL = {c4.x, c4.y}, cH = {c4.z, c4.w};
                hA[k*2+0] = aL * hA[k*2+0] + bL * x0;
                hA[k*2+1] = aH * hA[k*2+1] + bH * x0;
                hB[k*2+0] = aL * hB[k*2+0] + bL * x1;
                hB[k*2+1] = aH * hB[k*2+1] + bH * x1;
                yA0 = hA[k*2+0] * cL + yA0;
                yB0 = hA[k*2+1] * cH + yB0;
                yA1 = hB[k*2+0] * cL + yA1;
                yB1 = hB[k*2+1] * cH + yB1;
            }
            f32x2 ypair;
            ypair.x = (yA0.x + yA0.y) + (yB0.x + yB0.y) + (q == 0 ? dpv0 * xc0 : 0.f);
            ypair.y = (yA1.x + yA1.y) + (yB1.x + yB1.y) + (q == 0 ? dpv1 * xc1 : 0.f);
            yred[pbuf][r][q][dl] = ypair;
        }
        pbuf ^= 1;
    }
    // drain: readout last tile's y
    __syncthreads();
    #pragma unroll
    for (int i2 = 0; i2 < 4; ++i2) {
        const int i = tid + i2 * 256;
        const int r = i >> 7, c = i & 127;
        const int cl2 = c & 63;
        float y = 0.f;
        if (c < 64) {
            #pragma unroll
            for (int q2 = 0; q2 < 4; ++q2) y += yred[pbuf^1][r][q2][cl2].x;
        } else {
            #pragma unroll
            for (int q2 = 0; q2 < 4; ++q2) y += yred[pbuf^1][r][q2][cl2].y;
        }
        ybuf[(row0 + (LCH-8) + r) * 2048 + blockIdx.x * 128 + c] = __float2bfloat16(y);
    }
    // chunk-final h, transposed layout [d][s]
    const long hb0 = ((long)(b * NCH + ch) * 2048 + d0) * 128;
    const long hb1 = ((long)(b * NCH + ch) * 2048 + d1) * 128;
    #pragma unroll
    for (int k = 0; k < 8; ++k) {
        *(float4*)&hbuf[hb0 + s0 + k*4] = make_float4(hA[k*2].x, hA[k*2].y, hA[k*2+1].x, hA[k*2+1].y);
        *(float4*)&hbuf[hb1 + s0 + k*4] = make_float4(hB[k*2].x, hB[k*2].y, hB[k*2+1].x, hB[k*2+1].y);
    }
}

// ---------------- phase B: cross-chunk combine; h_in -> hi/lo bf16 (transposed) + hT ----------------
__global__ __launch_bounds__(256) void scan_comb(const float* __restrict__ hbuf,
                                                 const float* __restrict__ cumdt,
                                                 const float* __restrict__ A_log,
                                                 bf16* __restrict__ hinH,
                                                 bf16* __restrict__ hinL,
                                                 float* __restrict__ hT) {
    const long idx = (long)blockIdx.x * 256 + threadIdx.x;   // over B*D*S, s fastest
    const int s = (int)(idx & 127);
    const int d = (int)((idx >> 7) & 2047);
    const int b = (int)(idx >> 18);
    const float As = -expf(A_log[s]);
    float hr = 0.f;
    for (int c = 0; c < NCH; ++c) {
        const long off = ((long)(b * NCH + c) * 2048 + d) * 128 + s;
        const float loc = hbuf[off];
        const bf16 hh = __float2bfloat16(hr);
        hinH[off] = hh;
        hinL[off] = __float2bfloat16(hr - __bfloat162float(hh));
        const float p = __expf(As * cumdt[(long)b * TLEN + c * LCH + (LCH - 1)]);
        hr = p * hr + loc;
    }
    hT[((long)b * 2048 + d) * 128 + s] = hr;
}

// ---------------- Cmod precompute: cmod[row,s] = C[row,s] * exp(As*cumdt[row]) (bf16) ----------------
__global__ __launch_bounds__(256) void cmod_build(const float* __restrict__ cumdt,
                                                  const float* __restrict__ bc,
                                                  const float* __restrict__ A_log,
                                                  bf16* __restrict__ cmod) {
    const long i = (long)blockIdx.x * 256 + threadIdx.x;   // over BT*128
    const int s = (int)(i & 127);
    const long row = i >> 7;
    const float As = -__expf(A_log[s]);
    cmod[i] = __float2bfloat16(bc[row*256 + 128 + s] * __expf(As * cumdt[row]));
}

// ---------------- phase C as GEMM: Y += Cmod(512x128) @ Hin(128x2048) per (b,ch) ----------------
__global__ __launch_bounds__(256) void corr_gemm(const bf16* __restrict__ cmod,
                                                 const bf16* __restrict__ hinH,
                                                 const bf16* __restrict__ hinL,
                                                 bf16* __restrict__ ybuf) {
    __shared__ __align__(16) bf16 sA[128*32];
    __shared__ __align__(16) bf16 sBh[128*32], sBl[128*32];
    const int tid  = threadIdx.x;
    const int lane = tid & 63;
    const int wave = tid >> 6;
    const int wr   = (wave >> 1) * 64;
    const int wc   = (wave & 1) * 64;
    const long arow0 = (long)blockIdx.x * 128;      // rows over BT (within one 512-chunk)
    const long bcol0 = (long)blockIdx.y * 128;      // channels
    const int b  = (int)(arow0 >> 12);
    const int ch = (int)((arow0 & 4095) >> 9);
    const char* gA = (const char*)cmod;             // [BT][128] bf16, 256 B rows
    const char* gH = (const char*)(hinH + (long)(b * NCH + ch) * 2048 * 128);
    const char* gL = (const char*)(hinL + (long)(b * NCH + ch) * 2048 * 128);

    f32x4 acc[4][4] = {};
    const int c1 = tid, c2 = tid + 256;
    for (int k0 = 0; k0 < 128; k0 += 32) {
        __syncthreads();
        gload_lds16(gA + (arow0 + (c1 >> 2))*256 + k0*2 + (c1 & 3)*16, (char*)sA + c1*16);
        gload_lds16(gA + (arow0 + (c2 >> 2))*256 + k0*2 + (c2 & 3)*16, (char*)sA + c2*16);
        gload_lds16(gH + (bcol0 + (c1 >> 2))*256 + k0*2 + (c1 & 3)*16, (char*)sBh + c1*16);
        gload_lds16(gH + (bcol0 + (c2 >> 2))*256 + k0*2 + (c2 & 3)*16, (char*)sBh + c2*16);
        gload_lds16(gL + (bcol0 + (c1 >> 2))*256 + k0*2 + (c1 & 3)*16, (char*)sBl + c1*16);
        gload_lds16(gL + (bcol0 + (c2 >> 2))*256 + k0*2 + (c2 & 3)*16, (char*)sBl + c2*16);
        __syncthreads();

        const int r    = lane & 15;
        const int koff = (lane >> 4) * 8;
        short8x af[4], bh[4], bl[4];
        #pragma unroll
        for (int m = 0; m < 4; ++m)
            af[m] = *(const short8x*)(sA + (wr + m*16 + r) * 32 + koff);
        #pragma unroll
        for (int n = 0; n < 4; ++n) {
            bh[n] = *(const short8x*)(sBh + (wc + n*16 + r) * 32 + koff);
            bl[n] = *(const short8x*)(sBl + (wc + n*16 + r) * 32 + koff);
        }
        #pragma unroll
        for (int m = 0; m < 4; ++m)
            #pragma unroll
            for (int n = 0; n < 4; ++n) {
                acc[m][n] = __builtin_amdgcn_mfma_f32_16x16x32_bf16(af[m], bh[n], acc[m][n], 0, 0, 0);
                acc[m][n] = __builtin_amdgcn_mfma_f32_16x16x32_bf16(af[m], bl[n], acc[m][n], 0, 0, 0);
            }
    }

    const int r4 = (lane >> 4) * 4;
    const int cl = lane & 15;
    #pragma unroll
    for (int m = 0; m < 4; ++m) {
        #pragma unroll
        for (int n = 0; n < 4; ++n) {
            const long row = arow0 + wr + m*16 + r4;
            const long col = bcol0 + wc + n*16 + cl;
            #pragma unroll
            for (int j = 0; j < 4; ++j) {
                const long o = (row + j) * 2048 + col;
                ybuf[o] = __float2bfloat16(__bfloat162float(ybuf[o]) + acc[m][n][j]);
            }
        }
    }
}

// ---------------- RMSNorm * norm_w * csilu(z): ygated bf16 written over z ----------------
__global__ __launch_bounds__(256) void rms_z(const bf16* __restrict__ ybuf,
                                             bf16* __restrict__ zg,
                                             const float* __restrict__ norm_w) {
    const long row = blockIdx.x;
    const int tid = threadIdx.x;
    float v[8];
    float ss = 0.f;
    #pragma unroll
    for (int i = 0; i < 8; ++i) {
        v[i] = __bfloat162float(ybuf[row * D_INNER + i*256 + tid]);
        ss += v[i] * v[i];
    }
    __shared__ float red[256];
    red[tid] = ss;
    __syncthreads();
    for (int o = 128; o > 0; o >>= 1) {
        if (tid < o) red[tid] += red[tid + o];
        __syncthreads();
    }
    const float scale = rsqrtf(red[0] * (1.f / D_INNER) + 1e-5f);
    #pragma unroll
    for (int i = 0; i < 8; ++i) {
        const int dd = i*256 + tid;
        const float z = __bfloat162float(zg[row * D_INNER + dd]);
        zg[row * D_INNER + dd] = __float2bfloat16(v[i] * scale * norm_w[dd] * csilu_fast(z));
    }
}

extern "C" void kernel_launch(void* const* d_in, const int* in_sizes, int n_in,
                              void* d_out, int out_size, void* d_ws, size_t ws_size,
                              hipStream_t stream) {
    const float* x      = (const float*)d_in[0];
    const float* in_w   = (const float*)d_in[1];   // (4353, 1024)
    const float* conv_w = (const float*)d_in[2];   // (2048, 1, 4)
    const float* A_log  = (const float*)d_in[3];   // (128,)
    const float* Dp     = (const float*)d_in[4];   // (2048,)
    const float* norm_w = (const float*)d_in[5];   // (2048,)
    const float* out_w  = (const float*)d_in[6];   // (1024, 2048)
    float* out = (float*)d_out;
    float* hT  = out + (long)BT * D_MODEL;

    char* ws = (char*)d_ws;
    size_t off = 0;
    auto alloc = [&](size_t bytes) { void* p = ws + off; off += (bytes + 255) & ~(size_t)255; return p; };
    bf16*  zg    = (bf16*) alloc((size_t)BT * D_INNER * 2);               //  67.1 MB: z -> ygated
    float* xm    = (float*)alloc((size_t)BT * D_INNER * 4);               // 134.2 MB: xm f32
    float* bcbuf = (float*)alloc((size_t)BT * 256 * 4);                   //  16.8 MB: B|C f32
    bf16*  w2b   = (bf16*) alloc((size_t)D_MODEL * D_INNER * 2);          //   4.2 MB
    float* hbuf  = (float*)alloc((size_t)NB * NCH * 128 * D_INNER * 4);   //  33.5 MB
    float* dts   = (float*)alloc((size_t)BT * 4);
    float* cumdt = (float*)alloc((size_t)BT * 4);
    // total ~256.0 MB (PROVEN).  Guarded.
    if (ws_size < off) return;

    // Aliases (lifetime-disjoint):
    bf16* whi = (bf16*)hbuf;                      // [split_w -> gemm1]; hbuf written by scan_local
    bf16* wlo = whi + (size_t)NCOLS * D_MODEL;
    bf16* xhi = (bf16*)d_out;                     // [split_x -> gemm1]
    bf16* xlo = xhi + (size_t)BT * D_MODEL;
    bf16* ybuf = (bf16*)d_out;                    // [scan_local -> rms_z], then gemm2 writes out
    bf16* hinH = (bf16*)xm;                       // [comb -> corr]; xm dead after scan_local
    bf16* hinL = hinH + (size_t)NB * NCH * D_INNER * 128;
    bf16* cmod = hinL + (size_t)NB * NCH * D_INNER * 128;   // 4.2 MB, still inside xm

    split_kernel<<<BT*D_MODEL/4/256, 256, 0, stream>>>(x, xhi, xlo, BT*D_MODEL/4);
    split_kernel<<<NCOLS*D_MODEL/4/256, 256, 0, stream>>>(in_w, whi, wlo, NCOLS*D_MODEL/4);
    cast_kernel<<<D_MODEL*D_INNER/4/256, 256, 0, stream>>>(out_w, w2b, D_MODEL*D_INNER/4);

    gemm1_split<<<dim3(BT/128, NCOLS/128), 256, 0, stream>>>(xhi, xlo, whi, wlo, zg, xm, bcbuf);
    dt_gemv<<<BT/4, 256, 0, stream>>>(x, in_w + (long)NCOLS * D_MODEL, dts);
    cumsum_chunks<<<NB*NCH, LCH, 0, stream>>>(dts, cumdt);
    scan_local<<<dim3(D_INNER/128, NCH, NB), 256, 0, stream>>>(dts, bcbuf, A_log, xm, conv_w, Dp, ybuf, hbuf);
    scan_comb<<<NB*128*D_INNER/256, 256, 0, stream>>>(hbuf, cumdt, A_log, hinH, hinL, hT);
    cmod_build<<<BT*128/256, 256, 0, stream>>>(cumdt, bcbuf, A_log, cmod);
    corr_gemm<<<dim3(BT/128, D_INNER/128), 256, 0, stream>>>(cmod, hinH, hinL, ybuf);
    rms_z<<<BT, 256, 0, stream>>>(ybuf, zg, norm_w);
    gemm2_mfma<<<dim3(BT/128, D_MODEL/128), 256, 0, stream>>>(zg, w2b, out);
}